// Round 3
// baseline (943.537 us; speedup 1.0000x reference)
//
#include <hip/hip_runtime.h>

typedef unsigned short u16;
typedef __bf16 bf16x8 __attribute__((ext_vector_type(8)));
typedef float  f32x4  __attribute__((ext_vector_type(4)));

__device__ __forceinline__ float b2f(u16 u) {
    unsigned int v = ((unsigned int)u) << 16;
    return __builtin_bit_cast(float, v);
}
__device__ __forceinline__ u16 f2b(float f) {
    unsigned int v = __builtin_bit_cast(unsigned int, f);
    v += 0x7fffu + ((v >> 16) & 1u);
    return (u16)(v >> 16);
}

// async global->LDS, 16B per lane; LDS dest = wave-uniform base + lane*16
#define GLD16(gp, lp) __builtin_amdgcn_global_load_lds( \
    (const __attribute__((address_space(1))) void*)(gp), \
    (__attribute__((address_space(3))) void*)(lp), 16, 0, 0)

// ---------------------------------------------------------------- prep kernels

__global__ __launch_bounds__(256) void convert_x(const float* __restrict__ x,
                                                 u16* __restrict__ xb) {
    size_t i = ((size_t)blockIdx.x * 256 + threadIdx.x) * 8;
    float4 v0 = *(const float4*)(x + i);
    float4 v1 = *(const float4*)(x + i + 4);
    ushort4 o0, o1;
    o0.x = f2b(v0.x); o0.y = f2b(v0.y); o0.z = f2b(v0.z); o0.w = f2b(v0.w);
    o1.x = f2b(v1.x); o1.y = f2b(v1.y); o1.z = f2b(v1.z); o1.w = f2b(v1.w);
    *(ushort4*)(xb + i)     = o0;
    *(ushort4*)(xb + i + 4) = o1;
}

// Wt[n][k] = bf16(W[k][n]), 1024x1024, LDS-tiled transpose
__global__ __launch_bounds__(256) void transpose_w(const float* __restrict__ W,
                                                   u16* __restrict__ Wt) {
    __shared__ float tile[64][65];
    int kt = (blockIdx.x & 15) * 64;
    int nt = (blockIdx.x >> 4) * 64;
    int tid = threadIdx.x;
    int r = tid >> 4, c4 = (tid & 15) * 4;
    #pragma unroll
    for (int p = 0; p < 4; ++p) {
        int k = kt + p * 16 + r;
        float4 v = *(const float4*)(W + (size_t)k * 1024 + nt + c4);
        tile[c4 + 0][p * 16 + r] = v.x;
        tile[c4 + 1][p * 16 + r] = v.y;
        tile[c4 + 2][p * 16 + r] = v.z;
        tile[c4 + 3][p * 16 + r] = v.w;
    }
    __syncthreads();
    #pragma unroll
    for (int p = 0; p < 4; ++p) {
        int nl = p * 16 + r;
        ushort4 o;
        o.x = f2b(tile[nl][c4 + 0]); o.y = f2b(tile[nl][c4 + 1]);
        o.z = f2b(tile[nl][c4 + 2]); o.w = f2b(tile[nl][c4 + 3]);
        *(ushort4*)(Wt + (size_t)(nt + nl) * 1024 + kt + c4) = o;
    }
}

// Wut[b][n][k] = bf16(Wu[k][n] * p_av[b][k])  (fold p_av into per-batch B)
__global__ __launch_bounds__(256) void wu_prime(const float* __restrict__ Wu,
                                                const float* __restrict__ p_av,
                                                u16* __restrict__ Wut) {
    __shared__ float tile[64][65];
    int kt = (blockIdx.x & 15) * 64;
    int nt = (blockIdx.x >> 4) * 64;
    int tid = threadIdx.x;
    int r = tid >> 4, c4 = (tid & 15) * 4;
    #pragma unroll
    for (int p = 0; p < 4; ++p) {
        int k = kt + p * 16 + r;
        float4 v = *(const float4*)(Wu + (size_t)k * 1024 + nt + c4);
        tile[c4 + 0][p * 16 + r] = v.x;
        tile[c4 + 1][p * 16 + r] = v.y;
        tile[c4 + 2][p * 16 + r] = v.z;
        tile[c4 + 3][p * 16 + r] = v.w;
    }
    __syncthreads();
    for (int b = 0; b < 8; ++b) {
        float4 pv = *(const float4*)(p_av + (size_t)b * 1024 + kt + c4);
        #pragma unroll
        for (int p = 0; p < 4; ++p) {
            int nl = p * 16 + r;
            ushort4 o;
            o.x = f2b(tile[nl][c4 + 0] * pv.x);
            o.y = f2b(tile[nl][c4 + 1] * pv.y);
            o.z = f2b(tile[nl][c4 + 2] * pv.z);
            o.w = f2b(tile[nl][c4 + 3] * pv.w);
            *(ushort4*)(Wut + ((size_t)b * 1024 + nt + nl) * 1024 + kt + c4) = o;
        }
    }
}

__global__ __launch_bounds__(256) void wat_prep(const float* __restrict__ Wa,
                                                u16* __restrict__ Wat) {
    int idx = blockIdx.x * 256 + threadIdx.x;   // 16384 = 16 h * 1024 k
    int h = idx >> 10, k = idx & 1023;
    Wat[idx] = f2b(Wa[(k << 4) + h]);
}

// Wbt[b][h][k] = bf16(Wb[k][h] * q_av[b][k])
__global__ __launch_bounds__(256) void wbt_prep(const float* __restrict__ Wb,
                                                const float* __restrict__ q_av,
                                                u16* __restrict__ Wbt) {
    int idx = blockIdx.x * 256 + threadIdx.x;   // 131072
    int b = idx >> 14, rem = idx & 16383;
    int h = rem >> 10, k = rem & 1023;
    Wbt[idx] = f2b(Wb[(k << 4) + h] * q_av[(b << 10) + k]);
}

__global__ __launch_bounds__(256) void bias_concat(const float* __restrict__ bq,
                                                   const float* __restrict__ bk,
                                                   const float* __restrict__ bv,
                                                   float* __restrict__ outb) {
    int i = blockIdx.x * 256 + threadIdx.x;     // 3072
    outb[i] = (i < 1024) ? bq[i] : (i < 2048 ? bk[i - 1024] : bv[i - 2048]);
}

// ---------------------------------------------------------------- main GEMM
// m201-style 8-phase schedule. 256x256 tile, BK=64, 8 waves (2M x 4N).
// LDS 128 KiB = 2-tile ring of 8 half-slots (16 KB each):
//   buf b: Ah0 | Ah1 | Bh0 | Bh1, each half = 2 k-slabs of [128 rows][32 elems].
// Quadrant phases per tile: p0=(mh0,nh0) p1=(mh1,nh0) p2=(mh1,nh1) p3=(mh0,nh1).
// Output mapping: row = mh*128 + wm*64 + mi*16 + ..., col = nh*128 + wn*32 + ni*16 + ...
// so each half-slot is consumed by exactly the 1-2 phases of its quadrant index:
//   last ds_read:  Bh0@p0 (regs held to p1), Ah1@p1 (held to p2), Bh1@p2 (held), Ah0@p3.
// Stage schedule (slot freed >=1 barrier before stage issue; ledger verified):
//   p0: tile t+1 {Ah0,Bh1} -> other buf      (slots freed end of prev p3/p2)
//   p2: tile t+2 {Bh0}     -> current buf    (slot freed end of p0)
//   p3: tile t+2 {Ah1}     -> current buf    (slot freed end of p1/p2)
// One counted wait per tile at end of p3: vmcnt(4) forces tile t+1 complete,
// leaves tile t+2's 4 loads in flight across the barrier (issue->wait >= 4 phases).
// LDS swizzle: 64 B rows, phys 16B-chunk = quad ^ ((l16>>1)&3), realized by
// pre-swizzled per-lane GLOBAL source (gload_lds dest is linear). 0 conflicts (R1-verified).
__global__ __launch_bounds__(512, 2)
void gemm_bf16(const u16* __restrict__ A, int lda,
               const u16* __restrict__ Bt,        // [N][K] bf16 (B^T)
               const float* __restrict__ bias,    // [N]
               const u16* __restrict__ addsrc, int ldadd,  // optional epilogue add
               u16* __restrict__ C, int ldc,
               int N, int K, int batch_rows) {    // batch_rows>0: Bt per-batch
    __shared__ u16 lds[65536];   // 128 KiB
    int ntiles = N >> 8;
    int bid = blockIdx.x;
    int mtiles = gridDim.x / ntiles;
    int tm, tn;
    if ((mtiles & 7) == 0) {
        int xcd = bid & 7, s = bid >> 3;
        int mper = mtiles >> 3;
        tm = xcd * mper + s / ntiles;
        tn = s - (s / ntiles) * ntiles;
    } else {
        tm = bid / ntiles; tn = bid - (bid / ntiles) * ntiles;
    }
    int m0 = tm << 8, n0 = tn << 8;
    if (batch_rows > 0) Bt += (size_t)(m0 / batch_rows) * (size_t)N * K;
    int tid = threadIdx.x, lane = tid & 63, w = tid >> 6;
    int wm = w >> 2, wn = w & 3;               // 2 M-waves x 4 N-waves
    int quad = lane >> 4, l16 = lane & 15;

    // ---- staging addressing (per-lane swizzled global source, linear LDS dest) ----
    int srow  = tid >> 2;                              // 0..127: row within half
    int schk  = ((tid & 3) ^ ((tid >> 3) & 3)) << 3;   // logical chunk for phys tid&3
    const u16* pAs = A  + (size_t)(m0 + srow) * lda + schk;
    const u16* pBs = Bt + (size_t)(n0 + srow) * K   + schk;
    int A128 = lda << 7, B128 = K << 7;                // 128 rows of elements
    int wdst = w << 9;                                 // wave's 1KB chunk in an 8KB slab

#define STG_A(bufb, mh, kel) do { \
    GLD16(pAs + ((mh) ? A128 : 0) + (kel),      &lds[(bufb) + (mh)*8192 + wdst]); \
    GLD16(pAs + ((mh) ? A128 : 0) + (kel) + 32, &lds[(bufb) + (mh)*8192 + 4096 + wdst]); } while (0)
#define STG_B(bufb, nh, kel) do { \
    GLD16(pBs + ((nh) ? B128 : 0) + (kel),      &lds[(bufb) + 16384 + (nh)*8192 + wdst]); \
    GLD16(pBs + ((nh) ? B128 : 0) + (kel) + 32, &lds[(bufb) + 16384 + (nh)*8192 + 4096 + wdst]); } while (0)

    // ---- fragment read addressing ----
    int physc8 = (quad ^ ((l16 >> 1) & 3)) << 3;       // phys 16B chunk * 8 u16
    int aBase = ((wm << 6) + l16) * 32 + physc8;       // A row (within half) * 32
    int bBase = 16384 + ((wn << 5) + l16) * 32 + physc8;

#define RDA(bufb, mh, kk, mi) (*(const bf16x8*)&lds[(bufb) + (mh)*8192 + (kk)*4096 + (mi)*512 + aBase])
#define RDB(bufb, nh, kk, ni) (*(const bf16x8*)&lds[(bufb) + (nh)*8192 + (kk)*4096 + (ni)*512 + bBase])
#define MFMA16 __builtin_amdgcn_mfma_f32_16x16x32_bf16
#define CFENCE asm volatile("" ::: "memory")
#define LGKM0  do { asm volatile("s_waitcnt lgkmcnt(0)" ::: "memory"); \
                    __builtin_amdgcn_sched_barrier(0); } while (0)

    f32x4 zero = {0.f, 0.f, 0.f, 0.f};
    f32x4 acc[8][4];                                   // [mh*4+mi][nh*2+ni]
    #pragma unroll
    for (int i = 0; i < 8; ++i)
        #pragma unroll
        for (int j = 0; j < 4; ++j) acc[i][j] = zero;

    // ---- prologue: tile0 fully; tile1 {Bh0, Ah1} (emulating t=-1 p2,p3) ----
    STG_A(0, 0, 0); STG_A(0, 1, 0); STG_B(0, 0, 0); STG_B(0, 1, 0);
    STG_B(32768, 0, 64); STG_A(32768, 1, 64);
    asm volatile("s_waitcnt vmcnt(4)" ::: "memory");   // tile0 landed; tile1 partial in flight
    __builtin_amdgcn_s_barrier();

    int nt = K >> 6;
    for (int t = 0; t < nt; ++t) {
        int bb = (t & 1) << 15;
        int ob = bb ^ 32768;
        int k1 = (t + 1) << 6, k2 = (t + 2) << 6;
        bool s1 = (t + 1) < nt, s2 = (t + 2) < nt;
        bf16x8 a[4][2], b[2][2];

        // ======== p0: quadrant (mh=0, nh=0) ========
        #pragma unroll
        for (int ni = 0; ni < 2; ++ni) { b[ni][0] = RDB(bb, 0, 0, ni); b[ni][1] = RDB(bb, 0, 1, ni); }
        #pragma unroll
        for (int mi = 0; mi < 4; ++mi) { a[mi][0] = RDA(bb, 0, 0, mi); a[mi][1] = RDA(bb, 0, 1, mi); }
        if (s1) { STG_A(ob, 0, k1); STG_B(ob, 1, k1); }
        CFENCE; __builtin_amdgcn_s_barrier();
        LGKM0;
        __builtin_amdgcn_s_setprio(1);
        #pragma unroll
        for (int kk = 0; kk < 2; ++kk)
            #pragma unroll
            for (int mi = 0; mi < 4; ++mi)
                #pragma unroll
                for (int ni = 0; ni < 2; ++ni)
                    acc[mi][ni] = MFMA16(a[mi][kk], b[ni][kk], acc[mi][ni], 0, 0, 0);
        __builtin_amdgcn_s_setprio(0);
        CFENCE; __builtin_amdgcn_s_barrier();

        // ======== p1: quadrant (mh=1, nh=0), B held ========
        #pragma unroll
        for (int mi = 0; mi < 4; ++mi) { a[mi][0] = RDA(bb, 1, 0, mi); a[mi][1] = RDA(bb, 1, 1, mi); }
        CFENCE; __builtin_amdgcn_s_barrier();
        LGKM0;
        __builtin_amdgcn_s_setprio(1);
        #pragma unroll
        for (int kk = 0; kk < 2; ++kk)
            #pragma unroll
            for (int mi = 0; mi < 4; ++mi)
                #pragma unroll
                for (int ni = 0; ni < 2; ++ni)
                    acc[4 + mi][ni] = MFMA16(a[mi][kk], b[ni][kk], acc[4 + mi][ni], 0, 0, 0);
        __builtin_amdgcn_s_setprio(0);
        CFENCE; __builtin_amdgcn_s_barrier();

        // ======== p2: quadrant (mh=1, nh=1), A held from p1 ========
        #pragma unroll
        for (int ni = 0; ni < 2; ++ni) { b[ni][0] = RDB(bb, 1, 0, ni); b[ni][1] = RDB(bb, 1, 1, ni); }
        if (s2) STG_B(bb, 0, k2);
        CFENCE; __builtin_amdgcn_s_barrier();
        LGKM0;
        __builtin_amdgcn_s_setprio(1);
        #pragma unroll
        for (int kk = 0; kk < 2; ++kk)
            #pragma unroll
            for (int mi = 0; mi < 4; ++mi)
                #pragma unroll
                for (int ni = 0; ni < 2; ++ni)
                    acc[4 + mi][2 + ni] = MFMA16(a[mi][kk], b[ni][kk], acc[4 + mi][2 + ni], 0, 0, 0);
        __builtin_amdgcn_s_setprio(0);
        CFENCE; __builtin_amdgcn_s_barrier();

        // ======== p3: quadrant (mh=0, nh=1), B held ========
        #pragma unroll
        for (int mi = 0; mi < 4; ++mi) { a[mi][0] = RDA(bb, 0, 0, mi); a[mi][1] = RDA(bb, 0, 1, mi); }
        if (s2) STG_A(bb, 1, k2);
        CFENCE; __builtin_amdgcn_s_barrier();
        LGKM0;
        __builtin_amdgcn_s_setprio(1);
        #pragma unroll
        for (int kk = 0; kk < 2; ++kk)
            #pragma unroll
            for (int mi = 0; mi < 4; ++mi)
                #pragma unroll
                for (int ni = 0; ni < 2; ++ni)
                    acc[mi][2 + ni] = MFMA16(a[mi][kk], b[ni][kk], acc[mi][2 + ni], 0, 0, 0);
        __builtin_amdgcn_s_setprio(0);
        // boundary wait: tile t+1 must be fully resident for the next iteration;
        // tile t+2's 4 loads (issued p2/p3) stay in flight across the barrier.
        if (s2)      asm volatile("s_waitcnt vmcnt(4)" ::: "memory");
        else if (s1) asm volatile("s_waitcnt vmcnt(0)" ::: "memory");
        __builtin_amdgcn_s_barrier();
    }

    // epilogue: C/D layout col=lane&15, row=quad*4+reg (verified m89/m91)
    #pragma unroll
    for (int mi8 = 0; mi8 < 8; ++mi8) {
        int mh = mi8 >> 2, mi = mi8 & 3;
        #pragma unroll
        for (int ni4 = 0; ni4 < 4; ++ni4) {
            int nh = ni4 >> 1, ni = ni4 & 1;
            int col = n0 + (nh << 7) + (wn << 5) + (ni << 4) + l16;
            float bv = bias[col];
            #pragma unroll
            for (int rg = 0; rg < 4; ++rg) {
                int rowg = m0 + (mh << 7) + (wm << 6) + (mi << 4) + (quad << 2) + rg;
                float vv = acc[mi8][ni4][rg] + bv;
                if (addsrc) vv += b2f(addsrc[(size_t)rowg * ldadd + col]);
                C[(size_t)rowg * ldc + col] = f2b(vv);
            }
        }
    }
#undef STG_A
#undef STG_B
#undef RDA
#undef RDB
#undef MFMA16
#undef CFENCE
#undef LGKM0
}

// ------------------------------------------------- score GEMM ([Nrows]x[16])
// out[b][h][s] = 0.125*(dot(A_row, Bt[h]) + bias16[h]) + mask[b][s]
// 256 rows/block, BK=64, 8 MFMA per barrier pair, XOR-swizzled LDS.
__global__ __launch_bounds__(256)
void score_gemm(const u16* __restrict__ A, int lda,
                const u16* __restrict__ Bt,     // [16][1024] bf16 (per batch if batched)
                const float* __restrict__ bias16,
                const float* __restrict__ mask, // [8][4096]
                float* __restrict__ outsc,      // [8][16][4096]
                int batched) {
    __shared__ u16 As[256 * 64];   // 32 KB
    __shared__ u16 Bs[16 * 64];    //  2 KB
    int m0 = blockIdx.x << 8;      // 256 rows per block (within one batch: 4096%256==0)
    int tid = threadIdx.x, lane = tid & 63, w = tid >> 6;
    int quad = lane >> 4, l16 = lane & 15;
    int rph = l16 & 7;
    int lrow = lane >> 3;
    int lkg  = (lane & 7) ^ lrow;
    const u16* Bb = Bt + (batched ? ((size_t)(m0 >> 12) << 14) : 0);

    int idxA = (m0 + (w << 6) + lrow) * lda + (lkg << 3);  // chunk c=w*8+j rows
    int stepA = lda << 3;
    int idxB = lrow * 1024 + (lkg << 3);                    // rows h = c*8+lrow

    f32x4 acc4[4];
    #pragma unroll
    for (int i = 0; i < 4; ++i) acc4[i] = (f32x4){0.f, 0.f, 0.f, 0.f};

    for (int kt = 0; kt < 1024; kt += 64) {
        __syncthreads();
        #pragma unroll
        for (int j = 0; j < 8; ++j) {
            int c = (w << 3) + j;
            GLD16(A + (idxA + j * stepA + kt), &As[c << 9]);
        }
        if (w < 2)
            GLD16(Bb + (idxB + w * 8192 + kt), &Bs[w << 9]);
        __syncthreads();
        #pragma unroll
        for (int kk = 0; kk < 2; ++kk) {
            int kg = (((kk << 2) + quad) ^ rph) << 3;
            bf16x8 b = *(const bf16x8*)&Bs[(l16 << 6) + kg];
            #pragma unroll
            for (int mi = 0; mi < 4; ++mi) {
                bf16x8 a = *(const bf16x8*)&As[(((w << 6) + (mi << 4) + l16) << 6) + kg];
                acc4[mi] = __builtin_amdgcn_mfma_f32_16x16x32_bf16(a, b, acc4[mi], 0, 0, 0);
            }
        }
    }
    int bidx = m0 >> 12;
    float bv = bias16[l16];
    float* orow = outsc + (((size_t)bidx << 4) + l16) * 4096;
    const float* mrow = mask + ((size_t)bidx << 12);
    #pragma unroll
    for (int mi = 0; mi < 4; ++mi) {
        int sbase = (m0 & 4095) + (w << 6) + (mi << 4) + (quad << 2);
        #pragma unroll
        for (int rg = 0; rg < 4; ++rg)
            orow[sbase + rg] = 0.125f * (acc4[mi][rg] + bv) + mrow[sbase + rg];
    }
}

// ------------------------------------- softmax over S + weighted pool per (b,h)
__global__ __launch_bounds__(256)
void pool_kernel(const float* __restrict__ score,   // [8][16][4096]
                 const u16* __restrict__ X, int ldx, // q or k rows, bf16
                 const float* __restrict__ mulvec,   // null or q_av [8][1024]
                 float* __restrict__ outav) {        // [8][1024]
    __shared__ float wbuf[4096];
    __shared__ float red[4];
    __shared__ float psum[16][64];
    int b = blockIdx.x >> 4, h = blockIdx.x & 15;
    int tid = threadIdx.x, lane = tid & 63, w = tid >> 6;
    const float* srow = score + (((size_t)b << 4) + h) * 4096;
    float mx = -1e30f;
    for (int s = tid; s < 4096; s += 256) mx = fmaxf(mx, srow[s]);
    for (int o = 32; o; o >>= 1) mx = fmaxf(mx, __shfl_xor(mx, o));
    if (lane == 0) red[w] = mx;
    __syncthreads();
    mx = fmaxf(fmaxf(red[0], red[1]), fmaxf(red[2], red[3]));
    __syncthreads();
    float sm = 0.f;
    for (int s = tid; s < 4096; s += 256) {
        float e = __expf(srow[s] - mx);
        wbuf[s] = e;
        sm += e;
    }
    for (int o = 32; o; o >>= 1) sm += __shfl_xor(sm, o);
    if (lane == 0) red[w] = sm;
    __syncthreads();
    float inv = 1.f / (red[0] + red[1] + red[2] + red[3]);
    int dg = (tid & 15) << 2;   // 4 of 64 dims in head
    int sc = tid >> 4;          // 16 s-chunks of 256
    const u16* base = X + ((size_t)(b << 12)) * ldx + (h << 6) + dg;
    float a0 = 0, a1 = 0, a2 = 0, a3 = 0;
    for (int s = sc << 8; s < (sc << 8) + 256; ++s) {
        float wv = wbuf[s];
        ushort4 uv = *(const ushort4*)(base + (size_t)s * ldx);
        a0 += wv * b2f(uv.x); a1 += wv * b2f(uv.y);
        a2 += wv * b2f(uv.z); a3 += wv * b2f(uv.w);
    }
    psum[sc][dg + 0] = a0; psum[sc][dg + 1] = a1;
    psum[sc][dg + 2] = a2; psum[sc][dg + 3] = a3;
    __syncthreads();
    if (tid < 64) {
        float t = 0.f;
        #pragma unroll
        for (int j = 0; j < 16; ++j) t += psum[j][tid];
        t *= inv;
        if (mulvec) t *= mulvec[((size_t)b << 10) + (h << 6) + tid];
        outav[((size_t)b << 10) + (h << 6) + tid] = t;
    }
}

// ---------------------------------------------------------------- layernorm
__global__ __launch_bounds__(256)
void ln_kernel(const u16* __restrict__ Z, const float* __restrict__ g,
               const float* __restrict__ bta, float* __restrict__ outp) {
    __shared__ float rs1[4], rs2[4];
    int row = blockIdx.x, tid = threadIdx.x;
    const u16* zr = Z + ((size_t)row << 10);
    ushort4 uv = *(const ushort4*)(zr + (tid << 2));
    float v0 = b2f(uv.x), v1 = b2f(uv.y), v2 = b2f(uv.z), v3 = b2f(uv.w);
    float s = v0 + v1 + v2 + v3;
    float s2 = v0 * v0 + v1 * v1 + v2 * v2 + v3 * v3;
    for (int o = 32; o; o >>= 1) { s += __shfl_xor(s, o); s2 += __shfl_xor(s2, o); }
    if ((tid & 63) == 0) { rs1[tid >> 6] = s; rs2[tid >> 6] = s2; }
    __syncthreads();
    float S = rs1[0] + rs1[1] + rs1[2] + rs1[3];
    float S2 = rs2[0] + rs2[1] + rs2[2] + rs2[3];
    float mean = S * (1.0f / 1024.0f);
    float var = S2 * (1.0f / 1024.0f) - mean * mean;
    float inv = rsqrtf(var + 1e-6f);
    int c = tid << 2;
    float4 o4;
    o4.x = (v0 - mean) * inv * g[c + 0] + bta[c + 0];
    o4.y = (v1 - mean) * inv * g[c + 1] + bta[c + 1];
    o4.z = (v2 - mean) * inv * g[c + 2] + bta[c + 2];
    o4.w = (v3 - mean) * inv * g[c + 3] + bta[c + 3];
    *(float4*)(outp + ((size_t)row << 10) + c) = o4;
}

// ---------------------------------------------------------------- launch

extern "C" void kernel_launch(void* const* d_in, const int* in_sizes, int n_in,
                              void* d_out, int out_size, void* d_ws, size_t ws_size,
                              hipStream_t stream) {
    (void)in_sizes; (void)n_in; (void)out_size;
    const float* x    = (const float*)d_in[0];
    const float* mask = (const float*)d_in[1];
    const float* Wq   = (const float*)d_in[2];
    const float* bq   = (const float*)d_in[3];
    const float* Wk   = (const float*)d_in[4];
    const float* bk   = (const float*)d_in[5];
    const float* Wv   = (const float*)d_in[6];
    const float* bv   = (const float*)d_in[7];
    const float* Wa   = (const float*)d_in[8];
    const float* ba   = (const float*)d_in[9];
    const float* Wb   = (const float*)d_in[10];
    const float* bb   = (const float*)d_in[11];
    const float* Wu   = (const float*)d_in[12];
    const float* bu   = (const float*)d_in[13];
    const float* Wo   = (const float*)d_in[14];
    const float* bo   = (const float*)d_in[15];
    const float* ln_g = (const float*)d_in[16];
    const float* ln_b = (const float*)d_in[17];
    float* outp = (float*)d_out;

    char* ws = (char*)d_ws;
    // layout (bytes, all 256-aligned)
    u16*   xb    = (u16*)(ws);                     //  67,108,864  x bf16; later aliased by z
    u16*   qkv   = (u16*)(ws + 67108864);          // 201,326,592  [32768][3072]; q-region aliased by t
    u16*   Wqkvt = (u16*)(ws + 268435456);         //   6,291,456
    u16*   Wot   = (u16*)(ws + 274726912);         //   2,097,152
    u16*   Wat   = (u16*)(ws + 276824064);         //      32,768
    u16*   Wbt   = (u16*)(ws + 276856832);         //     262,144
    float* score = (float*)(ws + 277118976);       //   2,097,152 (reused for a & b scores)
    float* q_av  = (float*)(ws + 279216128);       //      32,768
    float* p_av  = (float*)(ws + 279248896);       //      32,768
    float* biasq = (float*)(ws + 279281664);       //      12,288
    u16*   Wubt  = (u16*)(ws + 279293952);         //  16,777,216  -> total 296,071,168
    if (ws_size < 296071168ULL) return;

    convert_x<<<16384, 256, 0, stream>>>(x, xb);
    transpose_w<<<256, 256, 0, stream>>>(Wq, Wqkvt);
    transpose_w<<<256, 256, 0, stream>>>(Wk, Wqkvt + 1048576);
    transpose_w<<<256, 256, 0, stream>>>(Wv, Wqkvt + 2097152);
    transpose_w<<<256, 256, 0, stream>>>(Wo, Wot);
    wat_prep<<<64, 256, 0, stream>>>(Wa, Wat);
    bias_concat<<<12, 256, 0, stream>>>(bq, bk, bv, biasq);

    // qkv = x @ [Wq|Wk|Wv] + bias   (M=32768, N=3072, K=1024), 256x256 tiles
    gemm_bf16<<<1536, 512, 0, stream>>>(xb, 1024, Wqkvt, biasq,
                                        nullptr, 0, qkv, 3072, 3072, 1024, 0);
    // ascore
    score_gemm<<<128, 256, 0, stream>>>(qkv, 3072, Wat, ba, mask, score, 0);
    // alpha softmax+pool -> q_av
    pool_kernel<<<128, 256, 0, stream>>>(score, qkv, 3072, nullptr, q_av);
    // per-batch Wb' = diag(q_av) Wb
    wbt_prep<<<512, 256, 0, stream>>>(Wb, q_av, Wbt);
    // bscore = k @ Wb'
    score_gemm<<<128, 256, 0, stream>>>(qkv + 1024, 3072, Wbt, bb, mask, score, 1);
    // beta softmax+pool, times q_av -> p_av
    pool_kernel<<<128, 256, 0, stream>>>(score, qkv + 1024, 3072, q_av, p_av);
    // per-batch Wu' = diag(p_av) Wu (transposed, bf16)
    wu_prime<<<256, 256, 0, stream>>>(Wu, p_av, Wubt);
    // t = v @ Wu'_b + bu + q   (writes over q region; element read-before-write)
    gemm_bf16<<<512, 512, 0, stream>>>(qkv + 2048, 3072, Wubt, bu,
                                       qkv, 3072, qkv, 3072, 1024, 1024, 4096);
    // z = t @ Wo^T + bo + x    (writes over xb; element read-before-write)
    gemm_bf16<<<512, 512, 0, stream>>>(qkv, 3072, Wot, bo,
                                       xb, 1024, xb, 1024, 1024, 1024, 0);
    // layernorm -> out (f32)
    ln_kernel<<<32768, 256, 0, stream>>>(xb, ln_g, ln_b, outp);
}

// Round 4
// 850.271 us; speedup vs baseline: 1.1097x; 1.1097x over previous
//
#include <hip/hip_runtime.h>

typedef unsigned short u16;
typedef __bf16 bf16x8 __attribute__((ext_vector_type(8)));
typedef float  f32x4  __attribute__((ext_vector_type(4)));

__device__ __forceinline__ float b2f(u16 u) {
    unsigned int v = ((unsigned int)u) << 16;
    return __builtin_bit_cast(float, v);
}
__device__ __forceinline__ u16 f2b(float f) {
    unsigned int v = __builtin_bit_cast(unsigned int, f);
    v += 0x7fffu + ((v >> 16) & 1u);
    return (u16)(v >> 16);
}

// async global->LDS, 16B per lane; LDS dest = wave-uniform base + lane*16
#define GLD16(gp, lp) __builtin_amdgcn_global_load_lds( \
    (const __attribute__((address_space(1))) void*)(gp), \
    (__attribute__((address_space(3))) void*)(lp), 16, 0, 0)

// ---------------------------------------------------------------- prep kernels

__global__ __launch_bounds__(256) void convert_x(const float* __restrict__ x,
                                                 u16* __restrict__ xb) {
    size_t i = ((size_t)blockIdx.x * 256 + threadIdx.x) * 8;
    float4 v0 = *(const float4*)(x + i);
    float4 v1 = *(const float4*)(x + i + 4);
    ushort4 o0, o1;
    o0.x = f2b(v0.x); o0.y = f2b(v0.y); o0.z = f2b(v0.z); o0.w = f2b(v0.w);
    o1.x = f2b(v1.x); o1.y = f2b(v1.y); o1.z = f2b(v1.z); o1.w = f2b(v1.w);
    *(ushort4*)(xb + i)     = o0;
    *(ushort4*)(xb + i + 4) = o1;
}

// Wt[n][k] = bf16(W[k][n]), 1024x1024, LDS-tiled transpose
__global__ __launch_bounds__(256) void transpose_w(const float* __restrict__ W,
                                                   u16* __restrict__ Wt) {
    __shared__ float tile[64][65];
    int kt = (blockIdx.x & 15) * 64;
    int nt = (blockIdx.x >> 4) * 64;
    int tid = threadIdx.x;
    int r = tid >> 4, c4 = (tid & 15) * 4;
    #pragma unroll
    for (int p = 0; p < 4; ++p) {
        int k = kt + p * 16 + r;
        float4 v = *(const float4*)(W + (size_t)k * 1024 + nt + c4);
        tile[c4 + 0][p * 16 + r] = v.x;
        tile[c4 + 1][p * 16 + r] = v.y;
        tile[c4 + 2][p * 16 + r] = v.z;
        tile[c4 + 3][p * 16 + r] = v.w;
    }
    __syncthreads();
    #pragma unroll
    for (int p = 0; p < 4; ++p) {
        int nl = p * 16 + r;
        ushort4 o;
        o.x = f2b(tile[nl][c4 + 0]); o.y = f2b(tile[nl][c4 + 1]);
        o.z = f2b(tile[nl][c4 + 2]); o.w = f2b(tile[nl][c4 + 3]);
        *(ushort4*)(Wt + (size_t)(nt + nl) * 1024 + kt + c4) = o;
    }
}

// Wut[b][n][k] = bf16(Wu[k][n] * p_av[b][k])  (fold p_av into per-batch B)
__global__ __launch_bounds__(256) void wu_prime(const float* __restrict__ Wu,
                                                const float* __restrict__ p_av,
                                                u16* __restrict__ Wut) {
    __shared__ float tile[64][65];
    int kt = (blockIdx.x & 15) * 64;
    int nt = (blockIdx.x >> 4) * 64;
    int tid = threadIdx.x;
    int r = tid >> 4, c4 = (tid & 15) * 4;
    #pragma unroll
    for (int p = 0; p < 4; ++p) {
        int k = kt + p * 16 + r;
        float4 v = *(const float4*)(Wu + (size_t)k * 1024 + nt + c4);
        tile[c4 + 0][p * 16 + r] = v.x;
        tile[c4 + 1][p * 16 + r] = v.y;
        tile[c4 + 2][p * 16 + r] = v.z;
        tile[c4 + 3][p * 16 + r] = v.w;
    }
    __syncthreads();
    for (int b = 0; b < 8; ++b) {
        float4 pv = *(const float4*)(p_av + (size_t)b * 1024 + kt + c4);
        #pragma unroll
        for (int p = 0; p < 4; ++p) {
            int nl = p * 16 + r;
            ushort4 o;
            o.x = f2b(tile[nl][c4 + 0] * pv.x);
            o.y = f2b(tile[nl][c4 + 1] * pv.y);
            o.z = f2b(tile[nl][c4 + 2] * pv.z);
            o.w = f2b(tile[nl][c4 + 3] * pv.w);
            *(ushort4*)(Wut + ((size_t)b * 1024 + nt + nl) * 1024 + kt + c4) = o;
        }
    }
}

__global__ __launch_bounds__(256) void wat_prep(const float* __restrict__ Wa,
                                                u16* __restrict__ Wat) {
    int idx = blockIdx.x * 256 + threadIdx.x;   // 16384 = 16 h * 1024 k
    int h = idx >> 10, k = idx & 1023;
    Wat[idx] = f2b(Wa[(k << 4) + h]);
}

// Wbt[b][h][k] = bf16(Wb[k][h] * q_av[b][k])
__global__ __launch_bounds__(256) void wbt_prep(const float* __restrict__ Wb,
                                                const float* __restrict__ q_av,
                                                u16* __restrict__ Wbt) {
    int idx = blockIdx.x * 256 + threadIdx.x;   // 131072
    int b = idx >> 14, rem = idx & 16383;
    int h = rem >> 10, k = rem & 1023;
    Wbt[idx] = f2b(Wb[(k << 4) + h] * q_av[(b << 10) + k]);
}

__global__ __launch_bounds__(256) void bias_concat(const float* __restrict__ bq,
                                                   const float* __restrict__ bk,
                                                   const float* __restrict__ bv,
                                                   float* __restrict__ outb) {
    int i = blockIdx.x * 256 + threadIdx.x;     // 3072
    outb[i] = (i < 1024) ? bq[i] : (i < 2048 ? bk[i - 1024] : bv[i - 2048]);
}

// ---------------------------------------------------------------- main GEMM
// 128x128 tile, BK=64, XOR-swizzled LDS (0 bank conflicts, verified),
// global_load_lds width=16, XCD-aware block swizzle. Proven 920 TF (R0).
// Register diet: 2 per-lane i32 indices + SGPR strides; __launch_bounds__(256,4)
// targets 128 regs/wave (64 AGPR acc + ~60 VGPR) -> 4 blocks/CU.
__global__ __launch_bounds__(256, 4)
void gemm_bf16(const u16* __restrict__ A, int lda,
               const u16* __restrict__ Bt,        // [N][K] bf16 (B^T)
               const float* __restrict__ bias,    // [N]
               const u16* __restrict__ addsrc, int ldadd,  // optional epilogue add
               u16* __restrict__ C, int ldc,
               int N, int K, int batch_rows) {    // batch_rows>0: Bt per-batch
    __shared__ u16 As[128 * 64];   // 16 KB, rows of 128 B, XOR-swizzled k-groups
    __shared__ u16 Bs[128 * 64];
    int ntiles = N >> 7;
    int bid = blockIdx.x;
    int mtiles = gridDim.x / ntiles;
    int tm, tn;
    if ((mtiles & 7) == 0) {
        int xcd = bid & 7, s = bid >> 3;
        int mper = mtiles >> 3;
        tm = xcd * mper + s / ntiles;
        tn = s - (s / ntiles) * ntiles;
    } else {
        tm = bid / ntiles; tn = bid - (bid / ntiles) * ntiles;
    }
    int m0 = tm << 7, n0 = tn << 7;
    if (batch_rows > 0) Bt += (size_t)(m0 / batch_rows) * (size_t)N * K;
    int tid = threadIdx.x, lane = tid & 63, w = tid >> 6;
    int wm = (w >> 1) << 6, wn = (w & 1) << 6;
    int quad = lane >> 4, l16 = lane & 15;
    int rph = l16 & 7;                 // row phase for XOR swizzle
    int lrow = lane >> 3;              // 0..7: row within 8-row chunk
    int lkg  = (lane & 7) ^ lrow;      // global k-group this lane fetches

    // per-lane 32-bit element indices; j/kt offsets are wave-uniform (SGPR)
    int idxA = (m0 + (w << 5) + lrow) * lda + (lkg << 3);
    int idxB = (n0 + (w << 5) + lrow) * K   + (lkg << 3);
    int stepA = lda << 3, stepB = K << 3;   // 8 rows of elements

    f32x4 zero = {0.f, 0.f, 0.f, 0.f};
    f32x4 acc[4][4];
    #pragma unroll
    for (int i = 0; i < 4; ++i)
        #pragma unroll
        for (int j = 0; j < 4; ++j) acc[i][j] = zero;

    for (int kt = 0; kt < K; kt += 64) {
        __syncthreads();
        #pragma unroll
        for (int j = 0; j < 4; ++j) {
            int c = (w << 2) + j;
            GLD16(A  + (idxA + j * stepA + kt), &As[c << 9]);
            GLD16(Bt + (idxB + j * stepB + kt), &Bs[c << 9]);
        }
        __syncthreads();
        #pragma unroll
        for (int kk = 0; kk < 2; ++kk) {
            bf16x8 a[4], b[4];
            int kg = (((kk << 2) + quad) ^ rph) << 3;  // swizzled k-offset (u16)
            #pragma unroll
            for (int i = 0; i < 4; ++i) {
                a[i] = *(const bf16x8*)&As[((wm + (i << 4) + l16) << 6) + kg];
                b[i] = *(const bf16x8*)&Bs[((wn + (i << 4) + l16) << 6) + kg];
            }
            #pragma unroll
            for (int mi = 0; mi < 4; ++mi)
                #pragma unroll
                for (int ni = 0; ni < 4; ++ni)
                    acc[mi][ni] = __builtin_amdgcn_mfma_f32_16x16x32_bf16(
                        a[mi], b[ni], acc[mi][ni], 0, 0, 0);
        }
    }
    // epilogue: C/D layout col=lane&15, row=quad*4+reg (verified m89/m91)
    #pragma unroll
    for (int mi = 0; mi < 4; ++mi) {
        #pragma unroll
        for (int ni = 0; ni < 4; ++ni) {
            int col = n0 + wn + (ni << 4) + l16;
            float bv = bias[col];
            #pragma unroll
            for (int rg = 0; rg < 4; ++rg) {
                int rowg = m0 + wm + (mi << 4) + (quad << 2) + rg;
                float vv = acc[mi][ni][rg] + bv;
                if (addsrc) vv += b2f(addsrc[(size_t)rowg * ldadd + col]);
                C[(size_t)rowg * ldc + col] = f2b(vv);
            }
        }
    }
}

// ------------------------------------------------- score GEMM ([Nrows]x[16])
// out[b][h][s] = 0.125*(dot(A_row, Bt[h]) + bias16[h]) + mask[b][s]
// 64 rows/block -> 512 blocks (2/CU), BK=64, XOR-swizzled LDS.
__global__ __launch_bounds__(256)
void score_gemm(const u16* __restrict__ A, int lda,
                const u16* __restrict__ Bt,     // [16][1024] bf16 (per batch if batched)
                const float* __restrict__ bias16,
                const float* __restrict__ mask, // [8][4096]
                float* __restrict__ outsc,      // [8][16][4096]
                int batched) {
    __shared__ u16 As[64 * 64];    // 8 KB
    __shared__ u16 Bs[16 * 64];    // 2 KB
    int m0 = blockIdx.x << 6;      // 64 rows per block (4096%64==0: no batch straddle)
    int tid = threadIdx.x, lane = tid & 63, w = tid >> 6;
    int quad = lane >> 4, l16 = lane & 15;
    int rph = l16 & 7;
    int lrow = lane >> 3;
    int lkg  = (lane & 7) ^ lrow;
    const u16* Bb = Bt + (batched ? ((size_t)(m0 >> 12) << 14) : 0);

    int idxA = (m0 + (w << 4) + lrow) * lda + (lkg << 3);  // chunk c=w*2+j, rows c*8+lrow
    int stepA = lda << 3;
    int idxB = lrow * 1024 + (lkg << 3);                    // rows h = w*8+lrow

    f32x4 acc4 = (f32x4){0.f, 0.f, 0.f, 0.f};

    for (int kt = 0; kt < 1024; kt += 64) {
        __syncthreads();
        #pragma unroll
        for (int j = 0; j < 2; ++j) {
            int c = (w << 1) + j;
            GLD16(A + (idxA + j * stepA + kt), &As[c << 9]);
        }
        if (w < 2)
            GLD16(Bb + (idxB + w * 8192 + kt), &Bs[w << 9]);
        __syncthreads();
        #pragma unroll
        for (int kk = 0; kk < 2; ++kk) {
            int kg = (((kk << 2) + quad) ^ rph) << 3;
            bf16x8 b = *(const bf16x8*)&Bs[(l16 << 6) + kg];
            bf16x8 a = *(const bf16x8*)&As[(((w << 4) + l16) << 6) + kg];
            acc4 = __builtin_amdgcn_mfma_f32_16x16x32_bf16(a, b, acc4, 0, 0, 0);
        }
    }
    int bidx = m0 >> 12;
    float bv = bias16[l16];
    float* orow = outsc + (((size_t)bidx << 4) + l16) * 4096;
    const float* mrow = mask + ((size_t)bidx << 12);
    int sbase = (m0 & 4095) + (w << 4) + (quad << 2);
    #pragma unroll
    for (int rg = 0; rg < 4; ++rg)
        orow[sbase + rg] = 0.125f * (acc4[rg] + bv) + mrow[sbase + rg];
}

// ---------------------------------------- softmax over S, normalize in place
__global__ __launch_bounds__(256)
void softmax_kernel(float* __restrict__ score) {   // [128][4096], one row per block
    __shared__ float wbuf[4096];
    __shared__ float red[4];
    int tid = threadIdx.x, lane = tid & 63, w = tid >> 6;
    float* srow = score + (size_t)blockIdx.x * 4096;
    float mx = -1e30f;
    for (int s = tid; s < 4096; s += 256) mx = fmaxf(mx, srow[s]);
    for (int o = 32; o; o >>= 1) mx = fmaxf(mx, __shfl_xor(mx, o));
    if (lane == 0) red[w] = mx;
    __syncthreads();
    mx = fmaxf(fmaxf(red[0], red[1]), fmaxf(red[2], red[3]));
    __syncthreads();
    float sm = 0.f;
    for (int s = tid; s < 4096; s += 256) {
        float e = __expf(srow[s] - mx);
        wbuf[s] = e;
        sm += e;
    }
    for (int o = 32; o; o >>= 1) sm += __shfl_xor(sm, o);
    if (lane == 0) red[w] = sm;
    __syncthreads();
    float inv = 1.f / (red[0] + red[1] + red[2] + red[3]);
    for (int s = tid; s < 4096; s += 256) srow[s] = wbuf[s] * inv;
}

// --------------------------- weighted pool partials: 1024 blocks = (b,h,chunk)
__global__ __launch_bounds__(256)
void pool_sum(const float* __restrict__ wn,     // [8][16][4096] normalized weights
              const u16* __restrict__ X, int ldx, // q or k rows, bf16
              float* __restrict__ part) {        // [128][8][64] partials
    __shared__ float psum[16][64];
    int blk = blockIdx.x, tid = threadIdx.x;
    int cc = blk & 7, bh = blk >> 3;            // chunk of 512 rows; (b,h)
    int b = bh >> 4, h = bh & 15;
    const float* wrow = wn + ((size_t)bh << 12) + (cc << 9);
    int dg = (tid & 15) << 2;                   // 4 of 64 dims in head
    int sc = tid >> 4;                          // 16 sub-chunks of 32 rows
    const u16* base = X + (size_t)((b << 12) + (cc << 9) + (sc << 5)) * ldx + (h << 6) + dg;
    float a0 = 0, a1 = 0, a2 = 0, a3 = 0;
    for (int s = 0; s < 32; ++s) {
        float wv = wrow[(sc << 5) + s];
        ushort4 uv = *(const ushort4*)(base + (size_t)s * ldx);
        a0 += wv * b2f(uv.x); a1 += wv * b2f(uv.y);
        a2 += wv * b2f(uv.z); a3 += wv * b2f(uv.w);
    }
    psum[sc][dg + 0] = a0; psum[sc][dg + 1] = a1;
    psum[sc][dg + 2] = a2; psum[sc][dg + 3] = a3;
    __syncthreads();
    if (tid < 64) {
        float t = 0.f;
        #pragma unroll
        for (int j = 0; j < 16; ++j) t += psum[j][tid];
        part[(((size_t)bh << 3) + cc) * 64 + tid] = t;
    }
}

// sum the 8 chunk-partials; optional elementwise multiply (p_av = pool * q_av)
__global__ __launch_bounds__(256)
void pool_finalize(const float* __restrict__ part,  // [128][8][64]
                   const float* __restrict__ mul,   // null or [8][1024]
                   float* __restrict__ outav) {     // [8][1024]
    int idx = blockIdx.x * 256 + threadIdx.x;       // 8192
    const float* p = part + ((size_t)(idx >> 6) << 9) + (idx & 63);
    float s = 0.f;
    #pragma unroll
    for (int c = 0; c < 8; ++c) s += p[c << 6];
    if (mul) s *= mul[idx];
    outav[idx] = s;
}

// ---------------------------------------------------------------- layernorm
__global__ __launch_bounds__(256)
void ln_kernel(const u16* __restrict__ Z, const float* __restrict__ g,
               const float* __restrict__ bta, float* __restrict__ outp) {
    __shared__ float rs1[4], rs2[4];
    int row = blockIdx.x, tid = threadIdx.x;
    const u16* zr = Z + ((size_t)row << 10);
    ushort4 uv = *(const ushort4*)(zr + (tid << 2));
    float v0 = b2f(uv.x), v1 = b2f(uv.y), v2 = b2f(uv.z), v3 = b2f(uv.w);
    float s = v0 + v1 + v2 + v3;
    float s2 = v0 * v0 + v1 * v1 + v2 * v2 + v3 * v3;
    for (int o = 32; o; o >>= 1) { s += __shfl_xor(s, o); s2 += __shfl_xor(s2, o); }
    if ((tid & 63) == 0) { rs1[tid >> 6] = s; rs2[tid >> 6] = s2; }
    __syncthreads();
    float S = rs1[0] + rs1[1] + rs1[2] + rs1[3];
    float S2 = rs2[0] + rs2[1] + rs2[2] + rs2[3];
    float mean = S * (1.0f / 1024.0f);
    float var = S2 * (1.0f / 1024.0f) - mean * mean;
    float inv = rsqrtf(var + 1e-6f);
    int c = tid << 2;
    float4 o4;
    o4.x = (v0 - mean) * inv * g[c + 0] + bta[c + 0];
    o4.y = (v1 - mean) * inv * g[c + 1] + bta[c + 1];
    o4.z = (v2 - mean) * inv * g[c + 2] + bta[c + 2];
    o4.w = (v3 - mean) * inv * g[c + 3] + bta[c + 3];
    *(float4*)(outp + ((size_t)row << 10) + c) = o4;
}

// ---------------------------------------------------------------- launch

extern "C" void kernel_launch(void* const* d_in, const int* in_sizes, int n_in,
                              void* d_out, int out_size, void* d_ws, size_t ws_size,
                              hipStream_t stream) {
    (void)in_sizes; (void)n_in; (void)out_size;
    const float* x    = (const float*)d_in[0];
    const float* mask = (const float*)d_in[1];
    const float* Wq   = (const float*)d_in[2];
    const float* bq   = (const float*)d_in[3];
    const float* Wk   = (const float*)d_in[4];
    const float* bk   = (const float*)d_in[5];
    const float* Wv   = (const float*)d_in[6];
    const float* bv   = (const float*)d_in[7];
    const float* Wa   = (const float*)d_in[8];
    const float* ba   = (const float*)d_in[9];
    const float* Wb   = (const float*)d_in[10];
    const float* bb   = (const float*)d_in[11];
    const float* Wu   = (const float*)d_in[12];
    const float* bu   = (const float*)d_in[13];
    const float* Wo   = (const float*)d_in[14];
    const float* bo   = (const float*)d_in[15];
    const float* ln_g = (const float*)d_in[16];
    const float* ln_b = (const float*)d_in[17];
    float* outp = (float*)d_out;

    char* ws = (char*)d_ws;
    // layout (bytes, all 256-aligned)
    u16*   xb    = (u16*)(ws);                     //  67,108,864  x bf16; later aliased by z
    u16*   qkv   = (u16*)(ws + 67108864);          // 201,326,592  [32768][3072]; q-region aliased by t
    u16*   Wqkvt = (u16*)(ws + 268435456);         //   6,291,456
    u16*   Wot   = (u16*)(ws + 274726912);         //   2,097,152
    u16*   Wat   = (u16*)(ws + 276824064);         //      32,768
    u16*   Wbt   = (u16*)(ws + 276856832);         //     262,144
    float* score = (float*)(ws + 277118976);       //   2,097,152 (reused for a & b scores)
    float* q_av  = (float*)(ws + 279216128);       //      32,768
    float* p_av  = (float*)(ws + 279248896);       //      32,768
    float* biasq = (float*)(ws + 279281664);       //      12,288
    u16*   Wubt  = (u16*)(ws + 279293952);         //  16,777,216
    float* part  = (float*)(ws + 296071168);       //     262,144  pool partials -> total 296,333,312
    if (ws_size < 296333312ULL) return;

    convert_x<<<16384, 256, 0, stream>>>(x, xb);
    transpose_w<<<256, 256, 0, stream>>>(Wq, Wqkvt);
    transpose_w<<<256, 256, 0, stream>>>(Wk, Wqkvt + 1048576);
    transpose_w<<<256, 256, 0, stream>>>(Wv, Wqkvt + 2097152);
    transpose_w<<<256, 256, 0, stream>>>(Wo, Wot);
    wat_prep<<<64, 256, 0, stream>>>(Wa, Wat);
    bias_concat<<<12, 256, 0, stream>>>(bq, bk, bv, biasq);

    // qkv = x @ [Wq|Wk|Wv] + bias   (M=32768, N=3072, K=1024)
    gemm_bf16<<<6144, 256, 0, stream>>>(xb, 1024, Wqkvt, biasq,
                                        nullptr, 0, qkv, 3072, 3072, 1024, 0);
    // ascore
    score_gemm<<<512, 256, 0, stream>>>(qkv, 3072, Wat, ba, mask, score, 0);
    // alpha softmax + pool -> q_av
    softmax_kernel<<<128, 256, 0, stream>>>(score);
    pool_sum<<<1024, 256, 0, stream>>>(score, qkv, 3072, part);
    pool_finalize<<<32, 256, 0, stream>>>(part, nullptr, q_av);
    // per-batch Wb' = diag(q_av) Wb
    wbt_prep<<<512, 256, 0, stream>>>(Wb, q_av, Wbt);
    // bscore = k @ Wb'
    score_gemm<<<512, 256, 0, stream>>>(qkv + 1024, 3072, Wbt, bb, mask, score, 1);
    // beta softmax + pool, times q_av -> p_av
    softmax_kernel<<<128, 256, 0, stream>>>(score);
    pool_sum<<<1024, 256, 0, stream>>>(score, qkv + 1024, 3072, part);
    pool_finalize<<<32, 256, 0, stream>>>(part, q_av, p_av);
    // per-batch Wu' = diag(p_av) Wu (transposed, bf16)
    wu_prime<<<256, 256, 0, stream>>>(Wu, p_av, Wubt);
    // t = v @ Wu'_b + bu + q   (writes over q region; element read-before-write)
    gemm_bf16<<<2048, 256, 0, stream>>>(qkv + 2048, 3072, Wubt, bu,
                                        qkv, 3072, qkv, 3072, 1024, 1024, 4096);
    // z = t @ Wo^T + bo + x    (writes over xb; element read-before-write)
    gemm_bf16<<<2048, 256, 0, stream>>>(qkv, 3072, Wot, bo,
                                        xb, 1024, xb, 1024, 1024, 1024, 0);
    // layernorm -> out (f32)
    ln_kernel<<<32768, 256, 0, stream>>>(xb, ln_g, ln_b, outp);
}

// Round 5
// 836.032 us; speedup vs baseline: 1.1286x; 1.0170x over previous
//
#include <hip/hip_runtime.h>

typedef unsigned short u16;
typedef __bf16 bf16x8 __attribute__((ext_vector_type(8)));
typedef float  f32x4  __attribute__((ext_vector_type(4)));

__device__ __forceinline__ float b2f(u16 u) {
    unsigned int v = ((unsigned int)u) << 16;
    return __builtin_bit_cast(float, v);
}
__device__ __forceinline__ u16 f2b(float f) {
    unsigned int v = __builtin_bit_cast(unsigned int, f);
    v += 0x7fffu + ((v >> 16) & 1u);
    return (u16)(v >> 16);
}

// async global->LDS, 16B per lane; LDS dest = wave-uniform base + lane*16
#define GLD16(gp, lp) __builtin_amdgcn_global_load_lds( \
    (const __attribute__((address_space(1))) void*)(gp), \
    (__attribute__((address_space(3))) void*)(lp), 16, 0, 0)

// ---------------------------------------------------------------- prep kernels

__global__ __launch_bounds__(256) void convert_x(const float* __restrict__ x,
                                                 u16* __restrict__ xb) {
    size_t i = ((size_t)blockIdx.x * 256 + threadIdx.x) * 8;
    float4 v0 = *(const float4*)(x + i);
    float4 v1 = *(const float4*)(x + i + 4);
    ushort4 o0, o1;
    o0.x = f2b(v0.x); o0.y = f2b(v0.y); o0.z = f2b(v0.z); o0.w = f2b(v0.w);
    o1.x = f2b(v1.x); o1.y = f2b(v1.y); o1.z = f2b(v1.z); o1.w = f2b(v1.w);
    *(ushort4*)(xb + i)     = o0;
    *(ushort4*)(xb + i + 4) = o1;
}

// fused weight prep: blocks 0..1023 transpose {Wq,Wk,Wv,Wo} (256 each),
// 1024..1087 wat, 1088..1099 bias concat. One launch instead of six.
__global__ __launch_bounds__(256)
void prep_all(const float* __restrict__ Wq, const float* __restrict__ Wk,
              const float* __restrict__ Wv, const float* __restrict__ Wo,
              u16* __restrict__ Wqkvt, u16* __restrict__ Wot,
              const float* __restrict__ Wa, u16* __restrict__ Wat,
              const float* __restrict__ bq, const float* __restrict__ bk,
              const float* __restrict__ bv, float* __restrict__ biasq) {
    __shared__ float tile[64][65];
    int blk = blockIdx.x;
    int tid = threadIdx.x;
    if (blk < 1024) {
        int g = blk >> 8;
        int lb = blk & 255;
        const float* W = (g == 0) ? Wq : (g == 1) ? Wk : (g == 2) ? Wv : Wo;
        u16* Wt = (g == 3) ? Wot : (Wqkvt + (size_t)g * 1048576);
        int kt = (lb & 15) * 64;
        int nt = (lb >> 4) * 64;
        int r = tid >> 4, c4 = (tid & 15) * 4;
        #pragma unroll
        for (int p = 0; p < 4; ++p) {
            int k = kt + p * 16 + r;
            float4 v = *(const float4*)(W + (size_t)k * 1024 + nt + c4);
            tile[c4 + 0][p * 16 + r] = v.x;
            tile[c4 + 1][p * 16 + r] = v.y;
            tile[c4 + 2][p * 16 + r] = v.z;
            tile[c4 + 3][p * 16 + r] = v.w;
        }
        __syncthreads();
        #pragma unroll
        for (int p = 0; p < 4; ++p) {
            int nl = p * 16 + r;
            ushort4 o;
            o.x = f2b(tile[nl][c4 + 0]); o.y = f2b(tile[nl][c4 + 1]);
            o.z = f2b(tile[nl][c4 + 2]); o.w = f2b(tile[nl][c4 + 3]);
            *(ushort4*)(Wt + (size_t)(nt + nl) * 1024 + kt + c4) = o;
        }
    } else if (blk < 1088) {
        int idx = (blk - 1024) * 256 + tid;   // 16384 = 16 h * 1024 k
        int h = idx >> 10, k = idx & 1023;
        Wat[idx] = f2b(Wa[(k << 4) + h]);
    } else {
        int i = (blk - 1088) * 256 + tid;     // 3072
        biasq[i] = (i < 1024) ? bq[i] : (i < 2048 ? bk[i - 1024] : bv[i - 2048]);
    }
}

// Wut[b][n][k] = bf16(Wu[k][n] * p_av[b][k])  (fold p_av into per-batch B)
__global__ __launch_bounds__(256) void wu_prime(const float* __restrict__ Wu,
                                                const float* __restrict__ p_av,
                                                u16* __restrict__ Wut) {
    __shared__ float tile[64][65];
    int kt = (blockIdx.x & 15) * 64;
    int nt = (blockIdx.x >> 4) * 64;
    int tid = threadIdx.x;
    int r = tid >> 4, c4 = (tid & 15) * 4;
    #pragma unroll
    for (int p = 0; p < 4; ++p) {
        int k = kt + p * 16 + r;
        float4 v = *(const float4*)(Wu + (size_t)k * 1024 + nt + c4);
        tile[c4 + 0][p * 16 + r] = v.x;
        tile[c4 + 1][p * 16 + r] = v.y;
        tile[c4 + 2][p * 16 + r] = v.z;
        tile[c4 + 3][p * 16 + r] = v.w;
    }
    __syncthreads();
    for (int b = 0; b < 8; ++b) {
        float4 pv = *(const float4*)(p_av + (size_t)b * 1024 + kt + c4);
        #pragma unroll
        for (int p = 0; p < 4; ++p) {
            int nl = p * 16 + r;
            ushort4 o;
            o.x = f2b(tile[nl][c4 + 0] * pv.x);
            o.y = f2b(tile[nl][c4 + 1] * pv.y);
            o.z = f2b(tile[nl][c4 + 2] * pv.z);
            o.w = f2b(tile[nl][c4 + 3] * pv.w);
            *(ushort4*)(Wut + ((size_t)b * 1024 + nt + nl) * 1024 + kt + c4) = o;
        }
    }
}

// Wbt[b][h][k] = bf16(Wb[k][h] * q_av[b][k])
__global__ __launch_bounds__(256) void wbt_prep(const float* __restrict__ Wb,
                                                const float* __restrict__ q_av,
                                                u16* __restrict__ Wbt) {
    int idx = blockIdx.x * 256 + threadIdx.x;   // 131072
    int b = idx >> 14, rem = idx & 16383;
    int h = rem >> 10, k = rem & 1023;
    Wbt[idx] = f2b(Wb[(k << 4) + h] * q_av[(b << 10) + k]);
}

// ---------------------------------------------------------------- main GEMM
// 128x128 tile, BK=64, XOR-swizzled LDS (0 bank conflicts, verified),
// global_load_lds width=16, XCD-aware block swizzle. Proven 920 TF (R0/R4).
__global__ __launch_bounds__(256, 4)
void gemm_bf16(const u16* __restrict__ A, int lda,
               const u16* __restrict__ Bt,        // [N][K] bf16 (B^T)
               const float* __restrict__ bias,    // [N]
               const u16* __restrict__ addsrc, int ldadd,  // optional epilogue add
               u16* __restrict__ C, int ldc,
               int N, int K, int batch_rows) {    // batch_rows>0: Bt per-batch
    __shared__ u16 As[128 * 64];   // 16 KB, rows of 128 B, XOR-swizzled k-groups
    __shared__ u16 Bs[128 * 64];
    int ntiles = N >> 7;
    int bid = blockIdx.x;
    int mtiles = gridDim.x / ntiles;
    int tm, tn;
    if ((mtiles & 7) == 0) {
        int xcd = bid & 7, s = bid >> 3;
        int mper = mtiles >> 3;
        tm = xcd * mper + s / ntiles;
        tn = s - (s / ntiles) * ntiles;
    } else {
        tm = bid / ntiles; tn = bid - (bid / ntiles) * ntiles;
    }
    int m0 = tm << 7, n0 = tn << 7;
    if (batch_rows > 0) Bt += (size_t)(m0 / batch_rows) * (size_t)N * K;
    int tid = threadIdx.x, lane = tid & 63, w = tid >> 6;
    int wm = (w >> 1) << 6, wn = (w & 1) << 6;
    int quad = lane >> 4, l16 = lane & 15;
    int rph = l16 & 7;                 // row phase for XOR swizzle
    int lrow = lane >> 3;              // 0..7: row within 8-row chunk
    int lkg  = (lane & 7) ^ lrow;      // global k-group this lane fetches

    int idxA = (m0 + (w << 5) + lrow) * lda + (lkg << 3);
    int idxB = (n0 + (w << 5) + lrow) * K   + (lkg << 3);
    int stepA = lda << 3, stepB = K << 3;   // 8 rows of elements

    f32x4 zero = {0.f, 0.f, 0.f, 0.f};
    f32x4 acc[4][4];
    #pragma unroll
    for (int i = 0; i < 4; ++i)
        #pragma unroll
        for (int j = 0; j < 4; ++j) acc[i][j] = zero;

    for (int kt = 0; kt < K; kt += 64) {
        __syncthreads();
        #pragma unroll
        for (int j = 0; j < 4; ++j) {
            int c = (w << 2) + j;
            GLD16(A  + (idxA + j * stepA + kt), &As[c << 9]);
            GLD16(Bt + (idxB + j * stepB + kt), &Bs[c << 9]);
        }
        __syncthreads();
        #pragma unroll
        for (int kk = 0; kk < 2; ++kk) {
            bf16x8 a[4], b[4];
            int kg = (((kk << 2) + quad) ^ rph) << 3;  // swizzled k-offset (u16)
            #pragma unroll
            for (int i = 0; i < 4; ++i) {
                a[i] = *(const bf16x8*)&As[((wm + (i << 4) + l16) << 6) + kg];
                b[i] = *(const bf16x8*)&Bs[((wn + (i << 4) + l16) << 6) + kg];
            }
            #pragma unroll
            for (int mi = 0; mi < 4; ++mi)
                #pragma unroll
                for (int ni = 0; ni < 4; ++ni)
                    acc[mi][ni] = __builtin_amdgcn_mfma_f32_16x16x32_bf16(
                        a[mi], b[ni], acc[mi][ni], 0, 0, 0);
        }
    }
    // epilogue: C/D layout col=lane&15, row=quad*4+reg (verified m89/m91)
    #pragma unroll
    for (int mi = 0; mi < 4; ++mi) {
        #pragma unroll
        for (int ni = 0; ni < 4; ++ni) {
            int col = n0 + wn + (ni << 4) + l16;
            float bv = bias[col];
            #pragma unroll
            for (int rg = 0; rg < 4; ++rg) {
                int rowg = m0 + wm + (mi << 4) + (quad << 2) + rg;
                float vv = acc[mi][ni][rg] + bv;
                if (addsrc) vv += b2f(addsrc[(size_t)rowg * ldadd + col]);
                C[(size_t)rowg * ldc + col] = f2b(vv);
            }
        }
    }
}

// ------------------------------------------------- score GEMM ([Nrows]x[16])
// out[b][h][s] = 0.125*(dot(A_row, Bt[h]) + bias16[h]) + mask[b][s]
// Also emits pmax[bh][sblk] = max over this block's 64 s-values (per h),
// so softmax needs no separate max pass. 64 rows/block -> 512 blocks.
__global__ __launch_bounds__(256)
void score_gemm(const u16* __restrict__ A, int lda,
                const u16* __restrict__ Bt,     // [16][1024] bf16 (per batch if batched)
                const float* __restrict__ bias16,
                const float* __restrict__ mask, // [8][4096]
                float* __restrict__ outsc,      // [8][16][4096]
                float* __restrict__ pmax,       // [128][64]
                int batched) {
    __shared__ u16 As[64 * 64];    // 8 KB
    __shared__ u16 Bs[16 * 64];    // 2 KB
    __shared__ float pm[16][16];   // [w*4+quad][h]
    int m0 = blockIdx.x << 6;      // 64 rows per block (4096%64==0: no batch straddle)
    int tid = threadIdx.x, lane = tid & 63, w = tid >> 6;
    int quad = lane >> 4, l16 = lane & 15;
    int rph = l16 & 7;
    int lrow = lane >> 3;
    int lkg  = (lane & 7) ^ lrow;
    const u16* Bb = Bt + (batched ? ((size_t)(m0 >> 12) << 14) : 0);

    int idxA = (m0 + (w << 4) + lrow) * lda + (lkg << 3);  // chunk c=w*2+j, rows c*8+lrow
    int stepA = lda << 3;
    int idxB = lrow * 1024 + (lkg << 3);                    // rows h = w*8+lrow

    f32x4 acc4 = (f32x4){0.f, 0.f, 0.f, 0.f};

    for (int kt = 0; kt < 1024; kt += 64) {
        __syncthreads();
        #pragma unroll
        for (int j = 0; j < 2; ++j) {
            int c = (w << 1) + j;
            GLD16(A + (idxA + j * stepA + kt), &As[c << 9]);
        }
        if (w < 2)
            GLD16(Bb + (idxB + w * 8192 + kt), &Bs[w << 9]);
        __syncthreads();
        #pragma unroll
        for (int kk = 0; kk < 2; ++kk) {
            int kg = (((kk << 2) + quad) ^ rph) << 3;
            bf16x8 b = *(const bf16x8*)&Bs[(l16 << 6) + kg];
            bf16x8 a = *(const bf16x8*)&As[(((w << 4) + l16) << 6) + kg];
            acc4 = __builtin_amdgcn_mfma_f32_16x16x32_bf16(a, b, acc4, 0, 0, 0);
        }
    }
    int bidx = m0 >> 12;
    float bv = bias16[l16];
    float* orow = outsc + (((size_t)bidx << 4) + l16) * 4096;
    const float* mrow = mask + ((size_t)bidx << 12);
    int sbase = (m0 & 4095) + (w << 4) + (quad << 2);
    float lm = -1e30f;
    #pragma unroll
    for (int rg = 0; rg < 4; ++rg) {
        float sv = 0.125f * (acc4[rg] + bv) + mrow[sbase + rg];
        orow[sbase + rg] = sv;
        lm = fmaxf(lm, sv);
    }
    pm[(w << 2) | quad][l16] = lm;
    __syncthreads();
    if (tid < 16) {
        float m = pm[0][tid];
        #pragma unroll
        for (int j = 1; j < 16; ++j) m = fmaxf(m, pm[j][tid]);
        pmax[(((bidx << 4) + tid) << 6) + (blockIdx.x & 63)] = m;
    }
}

// --------------------------- weighted pool partials: 1024 blocks = (b,h,chunk)
// Reads raw scores + pmax; applies exp(s - rowmax) on the fly; accumulates
// weighted sums AND exp-sum. Softmax normalization happens in pool_finalize.
__global__ __launch_bounds__(256)
void pool_sum(const float* __restrict__ score,  // [8][16][4096] raw scores
              const float* __restrict__ pmax,   // [128][64]
              const u16* __restrict__ X, int ldx, // q or k rows, bf16
              float* __restrict__ part,          // [128][8][64] weighted partials
              float* __restrict__ parte) {       // [128][8] exp-sum partials
    __shared__ float psum[16][64];
    __shared__ float pes[16];
    __shared__ float smx;
    int blk = blockIdx.x, tid = threadIdx.x;
    int cc = blk & 7, bh = blk >> 3;            // chunk of 512 rows; (b,h)
    int b = bh >> 4, h = bh & 15;
    if (tid < 64) {
        float m = pmax[(bh << 6) + tid];
        for (int o = 32; o; o >>= 1) m = fmaxf(m, __shfl_xor(m, o));
        if (tid == 0) smx = m;
    }
    __syncthreads();
    float mx = smx;
    const float* wrow = score + ((size_t)bh << 12) + (cc << 9);
    int dg = (tid & 15) << 2;                   // 4 of 64 dims in head
    int sc = tid >> 4;                          // 16 sub-chunks of 32 rows
    const u16* base = X + (size_t)((b << 12) + (cc << 9) + (sc << 5)) * ldx + (h << 6) + dg;
    float a0 = 0, a1 = 0, a2 = 0, a3 = 0, es = 0;
    for (int s = 0; s < 32; ++s) {
        float e = __expf(wrow[(sc << 5) + s] - mx);
        es += e;
        ushort4 uv = *(const ushort4*)(base + (size_t)s * ldx);
        a0 += e * b2f(uv.x); a1 += e * b2f(uv.y);
        a2 += e * b2f(uv.z); a3 += e * b2f(uv.w);
    }
    psum[sc][dg + 0] = a0; psum[sc][dg + 1] = a1;
    psum[sc][dg + 2] = a2; psum[sc][dg + 3] = a3;
    if ((tid & 15) == 0) pes[sc] = es;
    __syncthreads();
    if (tid < 64) {
        float t = 0.f;
        #pragma unroll
        for (int j = 0; j < 16; ++j) t += psum[j][tid];
        part[(((size_t)bh << 3) + cc) * 64 + tid] = t;
    }
    if (tid == 64) {
        float e = 0.f;
        #pragma unroll
        for (int j = 0; j < 16; ++j) e += pes[j];
        parte[(bh << 3) + cc] = e;
    }
}

// sum the 8 chunk-partials, divide by total exp-sum; optional multiply
__global__ __launch_bounds__(256)
void pool_finalize(const float* __restrict__ part,   // [128][8][64]
                   const float* __restrict__ parte,  // [128][8]
                   const float* __restrict__ mul,    // null or [8][1024]
                   float* __restrict__ outav) {      // [8][1024]
    int idx = blockIdx.x * 256 + threadIdx.x;        // 8192
    int bh = idx >> 6;
    const float* p = part + ((size_t)bh << 9) + (idx & 63);
    const float* pe = parte + (bh << 3);
    float s = 0.f, e = 0.f;
    #pragma unroll
    for (int c = 0; c < 8; ++c) { s += p[c << 6]; e += pe[c]; }
    s /= e;
    if (mul) s *= mul[idx];
    outav[idx] = s;
}

// ---------------------------------------------------------------- layernorm
__global__ __launch_bounds__(256)
void ln_kernel(const u16* __restrict__ Z, const float* __restrict__ g,
               const float* __restrict__ bta, float* __restrict__ outp) {
    __shared__ float rs1[4], rs2[4];
    int row = blockIdx.x, tid = threadIdx.x;
    const u16* zr = Z + ((size_t)row << 10);
    ushort4 uv = *(const ushort4*)(zr + (tid << 2));
    float v0 = b2f(uv.x), v1 = b2f(uv.y), v2 = b2f(uv.z), v3 = b2f(uv.w);
    float s = v0 + v1 + v2 + v3;
    float s2 = v0 * v0 + v1 * v1 + v2 * v2 + v3 * v3;
    for (int o = 32; o; o >>= 1) { s += __shfl_xor(s, o); s2 += __shfl_xor(s2, o); }
    if ((tid & 63) == 0) { rs1[tid >> 6] = s; rs2[tid >> 6] = s2; }
    __syncthreads();
    float S = rs1[0] + rs1[1] + rs1[2] + rs1[3];
    float S2 = rs2[0] + rs2[1] + rs2[2] + rs2[3];
    float mean = S * (1.0f / 1024.0f);
    float var = S2 * (1.0f / 1024.0f) - mean * mean;
    float inv = rsqrtf(var + 1e-6f);
    int c = tid << 2;
    float4 o4;
    o4.x = (v0 - mean) * inv * g[c + 0] + bta[c + 0];
    o4.y = (v1 - mean) * inv * g[c + 1] + bta[c + 1];
    o4.z = (v2 - mean) * inv * g[c + 2] + bta[c + 2];
    o4.w = (v3 - mean) * inv * g[c + 3] + bta[c + 3];
    *(float4*)(outp + ((size_t)row << 10) + c) = o4;
}

// ---------------------------------------------------------------- launch

extern "C" void kernel_launch(void* const* d_in, const int* in_sizes, int n_in,
                              void* d_out, int out_size, void* d_ws, size_t ws_size,
                              hipStream_t stream) {
    (void)in_sizes; (void)n_in; (void)out_size;
    const float* x    = (const float*)d_in[0];
    const float* mask = (const float*)d_in[1];
    const float* Wq   = (const float*)d_in[2];
    const float* bq   = (const float*)d_in[3];
    const float* Wk   = (const float*)d_in[4];
    const float* bk   = (const float*)d_in[5];
    const float* Wv   = (const float*)d_in[6];
    const float* bv   = (const float*)d_in[7];
    const float* Wa   = (const float*)d_in[8];
    const float* ba   = (const float*)d_in[9];
    const float* Wb   = (const float*)d_in[10];
    const float* bb   = (const float*)d_in[11];
    const float* Wu   = (const float*)d_in[12];
    const float* bu   = (const float*)d_in[13];
    const float* Wo   = (const float*)d_in[14];
    const float* bo   = (const float*)d_in[15];
    const float* ln_g = (const float*)d_in[16];
    const float* ln_b = (const float*)d_in[17];
    float* outp = (float*)d_out;

    char* ws = (char*)d_ws;
    // layout (bytes, all 256-aligned)
    u16*   xb    = (u16*)(ws);                     //  67,108,864  x bf16; later aliased by z
    u16*   qkv   = (u16*)(ws + 67108864);          // 201,326,592  [32768][3072]; q-region aliased by t
    u16*   Wqkvt = (u16*)(ws + 268435456);         //   6,291,456
    u16*   Wot   = (u16*)(ws + 274726912);         //   2,097,152
    u16*   Wat   = (u16*)(ws + 276824064);         //      32,768
    u16*   Wbt   = (u16*)(ws + 276856832);         //     262,144
    float* score = (float*)(ws + 277118976);       //   2,097,152 (reused for a & b scores)
    float* q_av  = (float*)(ws + 279216128);       //      32,768
    float* p_av  = (float*)(ws + 279248896);       //      32,768
    float* biasq = (float*)(ws + 279281664);       //      12,288
    u16*   Wubt  = (u16*)(ws + 279293952);         //  16,777,216
    float* part  = (float*)(ws + 296071168);       //     262,144  pool partials
    float* pmax  = (float*)(ws + 296333312);       //      32,768  per-block score maxes
    float* parte = (float*)(ws + 296366080);       //       4,096  exp-sum partials -> total 296,370,176
    if (ws_size < 296370176ULL) return;

    convert_x<<<16384, 256, 0, stream>>>(x, xb);
    prep_all<<<1100, 256, 0, stream>>>(Wq, Wk, Wv, Wo, Wqkvt, Wot, Wa, Wat,
                                       bq, bk, bv, biasq);

    // qkv = x @ [Wq|Wk|Wv] + bias   (M=32768, N=3072, K=1024)
    gemm_bf16<<<6144, 256, 0, stream>>>(xb, 1024, Wqkvt, biasq,
                                        nullptr, 0, qkv, 3072, 3072, 1024, 0);
    // ascore (+ per-block maxes)
    score_gemm<<<512, 256, 0, stream>>>(qkv, 3072, Wat, ba, mask, score, pmax, 0);
    // alpha pool (softmax folded in) -> q_av
    pool_sum<<<1024, 256, 0, stream>>>(score, pmax, qkv, 3072, part, parte);
    pool_finalize<<<32, 256, 0, stream>>>(part, parte, nullptr, q_av);
    // per-batch Wb' = diag(q_av) Wb
    wbt_prep<<<512, 256, 0, stream>>>(Wb, q_av, Wbt);
    // bscore = k @ Wb'
    score_gemm<<<512, 256, 0, stream>>>(qkv + 1024, 3072, Wbt, bb, mask, score, pmax, 1);
    // beta pool, times q_av -> p_av
    pool_sum<<<1024, 256, 0, stream>>>(score, pmax, qkv + 1024, 3072, part, parte);
    pool_finalize<<<32, 256, 0, stream>>>(part, parte, q_av, p_av);
    // per-batch Wu' = diag(p_av) Wu (transposed, bf16)
    wu_prime<<<256, 256, 0, stream>>>(Wu, p_av, Wubt);
    // t = v @ Wu'_b + bu + q   (writes over q region; element read-before-write)
    gemm_bf16<<<2048, 256, 0, stream>>>(qkv + 2048, 3072, Wubt, bu,
                                        qkv, 3072, qkv, 3072, 1024, 1024, 4096);
    // z = t @ Wo^T + bo + x    (writes over xb; element read-before-write)
    gemm_bf16<<<2048, 256, 0, stream>>>(qkv, 3072, Wot, bo,
                                        xb, 1024, xb, 1024, 1024, 1024, 0);
    // layernorm -> out (f32)
    ln_kernel<<<32768, 256, 0, stream>>>(xb, ln_g, ln_b, outp);
}

// Round 6
// 763.211 us; speedup vs baseline: 1.2363x; 1.0954x over previous
//
#include <hip/hip_runtime.h>

typedef unsigned short u16;
typedef __bf16 bf16x8 __attribute__((ext_vector_type(8)));
typedef float  f32x4  __attribute__((ext_vector_type(4)));

__device__ __forceinline__ float b2f(u16 u) {
    unsigned int v = ((unsigned int)u) << 16;
    return __builtin_bit_cast(float, v);
}
__device__ __forceinline__ u16 f2b(float f) {
    unsigned int v = __builtin_bit_cast(unsigned int, f);
    v += 0x7fffu + ((v >> 16) & 1u);
    return (u16)(v >> 16);
}

// async global->LDS, 16B per lane; LDS dest = wave-uniform base + lane*16
#define GLD16(gp, lp) __builtin_amdgcn_global_load_lds( \
    (const __attribute__((address_space(1))) void*)(gp), \
    (__attribute__((address_space(3))) void*)(lp), 16, 0, 0)

// ---------------------------------------------------------------- prep kernels

// fused: blocks 0..16383 convert x f32->bf16; 16384..17407 transpose
// {Wq,Wk,Wv,Wo}; 17408..17471 wat; 17472..17483 bias concat.
__global__ __launch_bounds__(256)
void prep_all(const float* __restrict__ x, u16* __restrict__ xb,
              const float* __restrict__ Wq, const float* __restrict__ Wk,
              const float* __restrict__ Wv, const float* __restrict__ Wo,
              u16* __restrict__ Wqkvt, u16* __restrict__ Wot,
              const float* __restrict__ Wa, u16* __restrict__ Wat,
              const float* __restrict__ bq, const float* __restrict__ bk,
              const float* __restrict__ bv, float* __restrict__ biasq) {
    __shared__ float tile[64][65];
    int blk = blockIdx.x;
    int tid = threadIdx.x;
    if (blk < 16384) {
        size_t i = ((size_t)blk * 256 + tid) * 8;
        float4 v0 = *(const float4*)(x + i);
        float4 v1 = *(const float4*)(x + i + 4);
        ushort4 o0, o1;
        o0.x = f2b(v0.x); o0.y = f2b(v0.y); o0.z = f2b(v0.z); o0.w = f2b(v0.w);
        o1.x = f2b(v1.x); o1.y = f2b(v1.y); o1.z = f2b(v1.z); o1.w = f2b(v1.w);
        *(ushort4*)(xb + i)     = o0;
        *(ushort4*)(xb + i + 4) = o1;
        return;
    }
    int wblk = blk - 16384;
    if (wblk < 1024) {
        int g = wblk >> 8;
        int lb = wblk & 255;
        const float* W = (g == 0) ? Wq : (g == 1) ? Wk : (g == 2) ? Wv : Wo;
        u16* Wt = (g == 3) ? Wot : (Wqkvt + (size_t)g * 1048576);
        int kt = (lb & 15) * 64;
        int nt = (lb >> 4) * 64;
        int r = tid >> 4, c4 = (tid & 15) * 4;
        #pragma unroll
        for (int p = 0; p < 4; ++p) {
            int k = kt + p * 16 + r;
            float4 v = *(const float4*)(W + (size_t)k * 1024 + nt + c4);
            tile[c4 + 0][p * 16 + r] = v.x;
            tile[c4 + 1][p * 16 + r] = v.y;
            tile[c4 + 2][p * 16 + r] = v.z;
            tile[c4 + 3][p * 16 + r] = v.w;
        }
        __syncthreads();
        #pragma unroll
        for (int p = 0; p < 4; ++p) {
            int nl = p * 16 + r;
            ushort4 o;
            o.x = f2b(tile[nl][c4 + 0]); o.y = f2b(tile[nl][c4 + 1]);
            o.z = f2b(tile[nl][c4 + 2]); o.w = f2b(tile[nl][c4 + 3]);
            *(ushort4*)(Wt + (size_t)(nt + nl) * 1024 + kt + c4) = o;
        }
    } else if (wblk < 1088) {
        int idx = (wblk - 1024) * 256 + tid;   // 16384 = 16 h * 1024 k
        int h = idx >> 10, k = idx & 1023;
        Wat[idx] = f2b(Wa[(k << 4) + h]);
    } else {
        int i = (wblk - 1088) * 256 + tid;     // 3072
        biasq[i] = (i < 1024) ? bq[i] : (i < 2048 ? bk[i - 1024] : bv[i - 2048]);
    }
}

// Wut[b][n][k] = bf16(Wu[k][n] * p_av[b][k])  (fold p_av into per-batch B)
__global__ __launch_bounds__(256) void wu_prime(const float* __restrict__ Wu,
                                                const float* __restrict__ p_av,
                                                u16* __restrict__ Wut) {
    __shared__ float tile[64][65];
    int kt = (blockIdx.x & 15) * 64;
    int nt = (blockIdx.x >> 4) * 64;
    int tid = threadIdx.x;
    int r = tid >> 4, c4 = (tid & 15) * 4;
    #pragma unroll
    for (int p = 0; p < 4; ++p) {
        int k = kt + p * 16 + r;
        float4 v = *(const float4*)(Wu + (size_t)k * 1024 + nt + c4);
        tile[c4 + 0][p * 16 + r] = v.x;
        tile[c4 + 1][p * 16 + r] = v.y;
        tile[c4 + 2][p * 16 + r] = v.z;
        tile[c4 + 3][p * 16 + r] = v.w;
    }
    __syncthreads();
    for (int b = 0; b < 8; ++b) {
        float4 pv = *(const float4*)(p_av + (size_t)b * 1024 + kt + c4);
        #pragma unroll
        for (int p = 0; p < 4; ++p) {
            int nl = p * 16 + r;
            ushort4 o;
            o.x = f2b(tile[nl][c4 + 0] * pv.x);
            o.y = f2b(tile[nl][c4 + 1] * pv.y);
            o.z = f2b(tile[nl][c4 + 2] * pv.z);
            o.w = f2b(tile[nl][c4 + 3] * pv.w);
            *(ushort4*)(Wut + ((size_t)b * 1024 + nt + nl) * 1024 + kt + c4) = o;
        }
    }
}

// Wbt[b][h][k] = bf16(Wb[k][h] * q_av[b][k])
__global__ __launch_bounds__(256) void wbt_prep(const float* __restrict__ Wb,
                                                const float* __restrict__ q_av,
                                                u16* __restrict__ Wbt) {
    int idx = blockIdx.x * 256 + threadIdx.x;   // 131072
    int b = idx >> 14, rem = idx & 16383;
    int h = rem >> 10, k = rem & 1023;
    Wbt[idx] = f2b(Wb[(k << 4) + h] * q_av[(b << 10) + k]);
}

// ---------------------------------------------------------------- main GEMM
// 128x128 tile, BK=64, XOR-swizzled LDS (0 bank conflicts, verified),
// global_load_lds width=16, XCD-aware block swizzle + 2x2 supertile ordering
// within each XCD (co-resident blocks share an A-pair and a B-pair; A-pair
// 524 KB stays L2-hot across the tn sweep -> kills the 7x A re-fetch seen in
// FETCH_SIZE=470MB vs 73MB ideal). Proven 920 TF (R0/R4/R5) + L2 fix.
__global__ __launch_bounds__(256, 4)
void gemm_bf16(const u16* __restrict__ A, int lda,
               const u16* __restrict__ Bt,        // [N][K] bf16 (B^T)
               const float* __restrict__ bias,    // [N]
               const u16* __restrict__ addsrc, int ldadd,  // optional epilogue add
               u16* __restrict__ C, int ldc,
               int N, int K, int batch_rows) {    // batch_rows>0: Bt per-batch
    __shared__ u16 As[128 * 64];   // 16 KB, rows of 128 B, XOR-swizzled k-groups
    __shared__ u16 Bs[128 * 64];
    int ntiles = N >> 7;
    int bid = blockIdx.x;
    int mtiles = gridDim.x / ntiles;
    int tm, tn;
    if ((mtiles & 7) == 0) {
        int xcd = bid & 7, s = bid >> 3;
        int mper = mtiles >> 3;
        if (((mper | ntiles) & 1) == 0) {
            // 2x2 supertile ordering: s -> (2x2 square index, corner)
            int half = ntiles >> 1;
            int sq = s >> 2, r = s & 3;
            tm = xcd * mper + ((sq / half) << 1) + (r >> 1);
            tn = ((sq - (sq / half) * half) << 1) + (r & 1);
        } else {
            tm = xcd * mper + s / ntiles;
            tn = s - (s / ntiles) * ntiles;
        }
    } else {
        tm = bid / ntiles; tn = bid - (bid / ntiles) * ntiles;
    }
    int m0 = tm << 7, n0 = tn << 7;
    if (batch_rows > 0) Bt += (size_t)(m0 / batch_rows) * (size_t)N * K;
    int tid = threadIdx.x, lane = tid & 63, w = tid >> 6;
    int wm = (w >> 1) << 6, wn = (w & 1) << 6;
    int quad = lane >> 4, l16 = lane & 15;
    int rph = l16 & 7;                 // row phase for XOR swizzle
    int lrow = lane >> 3;              // 0..7: row within 8-row chunk
    int lkg  = (lane & 7) ^ lrow;      // global k-group this lane fetches

    int idxA = (m0 + (w << 5) + lrow) * lda + (lkg << 3);
    int idxB = (n0 + (w << 5) + lrow) * K   + (lkg << 3);
    int stepA = lda << 3, stepB = K << 3;   // 8 rows of elements

    f32x4 zero = {0.f, 0.f, 0.f, 0.f};
    f32x4 acc[4][4];
    #pragma unroll
    for (int i = 0; i < 4; ++i)
        #pragma unroll
        for (int j = 0; j < 4; ++j) acc[i][j] = zero;

    for (int kt = 0; kt < K; kt += 64) {
        __syncthreads();
        #pragma unroll
        for (int j = 0; j < 4; ++j) {
            int c = (w << 2) + j;
            GLD16(A  + (idxA + j * stepA + kt), &As[c << 9]);
            GLD16(Bt + (idxB + j * stepB + kt), &Bs[c << 9]);
        }
        __syncthreads();
        #pragma unroll
        for (int kk = 0; kk < 2; ++kk) {
            bf16x8 a[4], b[4];
            int kg = (((kk << 2) + quad) ^ rph) << 3;  // swizzled k-offset (u16)
            #pragma unroll
            for (int i = 0; i < 4; ++i) {
                a[i] = *(const bf16x8*)&As[((wm + (i << 4) + l16) << 6) + kg];
                b[i] = *(const bf16x8*)&Bs[((wn + (i << 4) + l16) << 6) + kg];
            }
            #pragma unroll
            for (int mi = 0; mi < 4; ++mi)
                #pragma unroll
                for (int ni = 0; ni < 4; ++ni)
                    acc[mi][ni] = __builtin_amdgcn_mfma_f32_16x16x32_bf16(
                        a[mi], b[ni], acc[mi][ni], 0, 0, 0);
        }
    }
    // epilogue: C/D layout col=lane&15, row=quad*4+reg (verified m89/m91).
    // addsrc loads batched per-mi ahead of the stores so vmcnt amortizes.
    #pragma unroll
    for (int mi = 0; mi < 4; ++mi) {
        u16 av[4][4];
        if (addsrc) {
            #pragma unroll
            for (int ni = 0; ni < 4; ++ni) {
                int col = n0 + wn + (ni << 4) + l16;
                #pragma unroll
                for (int rg = 0; rg < 4; ++rg) {
                    int rowg = m0 + wm + (mi << 4) + (quad << 2) + rg;
                    av[ni][rg] = addsrc[(size_t)rowg * ldadd + col];
                }
            }
        }
        #pragma unroll
        for (int ni = 0; ni < 4; ++ni) {
            int col = n0 + wn + (ni << 4) + l16;
            float bv = bias[col];
            #pragma unroll
            for (int rg = 0; rg < 4; ++rg) {
                int rowg = m0 + wm + (mi << 4) + (quad << 2) + rg;
                float vv = acc[mi][ni][rg] + bv;
                if (addsrc) vv += b2f(av[ni][rg]);
                C[(size_t)rowg * ldc + col] = f2b(vv);
            }
        }
    }
}

// ------------------------------------------------- score GEMM ([Nrows]x[16])
// out[b][h][s] = 0.125*(dot(A_row, Bt[h]) + bias16[h]) + mask[b][s]
// Also emits pmax[bh][sblk] = max over this block's 64 s-values (per h),
// so softmax needs no separate max pass. 64 rows/block -> 512 blocks.
__global__ __launch_bounds__(256)
void score_gemm(const u16* __restrict__ A, int lda,
                const u16* __restrict__ Bt,     // [16][1024] bf16 (per batch if batched)
                const float* __restrict__ bias16,
                const float* __restrict__ mask, // [8][4096]
                float* __restrict__ outsc,      // [8][16][4096]
                float* __restrict__ pmax,       // [128][64]
                int batched) {
    __shared__ u16 As[64 * 64];    // 8 KB
    __shared__ u16 Bs[16 * 64];    // 2 KB
    __shared__ float pm[16][16];   // [w*4+quad][h]
    int m0 = blockIdx.x << 6;      // 64 rows per block (4096%64==0: no batch straddle)
    int tid = threadIdx.x, lane = tid & 63, w = tid >> 6;
    int quad = lane >> 4, l16 = lane & 15;
    int rph = l16 & 7;
    int lrow = lane >> 3;
    int lkg  = (lane & 7) ^ lrow;
    const u16* Bb = Bt + (batched ? ((size_t)(m0 >> 12) << 14) : 0);

    int idxA = (m0 + (w << 4) + lrow) * lda + (lkg << 3);  // chunk c=w*2+j, rows c*8+lrow
    int stepA = lda << 3;
    int idxB = lrow * 1024 + (lkg << 3);                    // rows h = w*8+lrow

    f32x4 acc4 = (f32x4){0.f, 0.f, 0.f, 0.f};

    for (int kt = 0; kt < 1024; kt += 64) {
        __syncthreads();
        #pragma unroll
        for (int j = 0; j < 2; ++j) {
            int c = (w << 1) + j;
            GLD16(A + (idxA + j * stepA + kt), &As[c << 9]);
        }
        if (w < 2)
            GLD16(Bb + (idxB + w * 8192 + kt), &Bs[w << 9]);
        __syncthreads();
        #pragma unroll
        for (int kk = 0; kk < 2; ++kk) {
            int kg = (((kk << 2) + quad) ^ rph) << 3;
            bf16x8 b = *(const bf16x8*)&Bs[(l16 << 6) + kg];
            bf16x8 a = *(const bf16x8*)&As[(((w << 4) + l16) << 6) + kg];
            acc4 = __builtin_amdgcn_mfma_f32_16x16x32_bf16(a, b, acc4, 0, 0, 0);
        }
    }
    int bidx = m0 >> 12;
    float bv = bias16[l16];
    float* orow = outsc + (((size_t)bidx << 4) + l16) * 4096;
    const float* mrow = mask + ((size_t)bidx << 12);
    int sbase = (m0 & 4095) + (w << 4) + (quad << 2);
    float lm = -1e30f;
    #pragma unroll
    for (int rg = 0; rg < 4; ++rg) {
        float sv = 0.125f * (acc4[rg] + bv) + mrow[sbase + rg];
        orow[sbase + rg] = sv;
        lm = fmaxf(lm, sv);
    }
    pm[(w << 2) | quad][l16] = lm;
    __syncthreads();
    if (tid < 16) {
        float m = pm[0][tid];
        #pragma unroll
        for (int j = 1; j < 16; ++j) m = fmaxf(m, pm[j][tid]);
        pmax[(((bidx << 4) + tid) << 6) + (blockIdx.x & 63)] = m;
    }
}

// --------------------------- weighted pool partials: 1024 blocks = (b,h,chunk)
// Reads raw scores + pmax; applies exp(s - rowmax) on the fly; accumulates
// weighted sums AND exp-sum. Softmax normalization happens in pool_finalize.
__global__ __launch_bounds__(256)
void pool_sum(const float* __restrict__ score,  // [8][16][4096] raw scores
              const float* __restrict__ pmax,   // [128][64]
              const u16* __restrict__ X, int ldx, // q or k rows, bf16
              float* __restrict__ part,          // [128][8][64] weighted partials
              float* __restrict__ parte) {       // [128][8] exp-sum partials
    __shared__ float psum[16][64];
    __shared__ float pes[16];
    __shared__ float smx;
    int blk = blockIdx.x, tid = threadIdx.x;
    int cc = blk & 7, bh = blk >> 3;            // chunk of 512 rows; (b,h)
    int b = bh >> 4, h = bh & 15;
    if (tid < 64) {
        float m = pmax[(bh << 6) + tid];
        for (int o = 32; o; o >>= 1) m = fmaxf(m, __shfl_xor(m, o));
        if (tid == 0) smx = m;
    }
    __syncthreads();
    float mx = smx;
    const float* wrow = score + ((size_t)bh << 12) + (cc << 9);
    int dg = (tid & 15) << 2;                   // 4 of 64 dims in head
    int sc = tid >> 4;                          // 16 sub-chunks of 32 rows
    const u16* base = X + (size_t)((b << 12) + (cc << 9) + (sc << 5)) * ldx + (h << 6) + dg;
    float a0 = 0, a1 = 0, a2 = 0, a3 = 0, es = 0;
    for (int s = 0; s < 32; ++s) {
        float e = __expf(wrow[(sc << 5) + s] - mx);
        es += e;
        ushort4 uv = *(const ushort4*)(base + (size_t)s * ldx);
        a0 += e * b2f(uv.x); a1 += e * b2f(uv.y);
        a2 += e * b2f(uv.z); a3 += e * b2f(uv.w);
    }
    psum[sc][dg + 0] = a0; psum[sc][dg + 1] = a1;
    psum[sc][dg + 2] = a2; psum[sc][dg + 3] = a3;
    if ((tid & 15) == 0) pes[sc] = es;
    __syncthreads();
    if (tid < 64) {
        float t = 0.f;
        #pragma unroll
        for (int j = 0; j < 16; ++j) t += psum[j][tid];
        part[(((size_t)bh << 3) + cc) * 64 + tid] = t;
    }
    if (tid == 64) {
        float e = 0.f;
        #pragma unroll
        for (int j = 0; j < 16; ++j) e += pes[j];
        parte[(bh << 3) + cc] = e;
    }
}

// sum the 8 chunk-partials, divide by total exp-sum; optional multiply
__global__ __launch_bounds__(256)
void pool_finalize(const float* __restrict__ part,   // [128][8][64]
                   const float* __restrict__ parte,  // [128][8]
                   const float* __restrict__ mul,    // null or [8][1024]
                   float* __restrict__ outav) {      // [8][1024]
    int idx = blockIdx.x * 256 + threadIdx.x;        // 8192
    int bh = idx >> 6;
    const float* p = part + ((size_t)bh << 9) + (idx & 63);
    const float* pe = parte + (bh << 3);
    float s = 0.f, e = 0.f;
    #pragma unroll
    for (int c = 0; c < 8; ++c) { s += p[c << 6]; e += pe[c]; }
    s /= e;
    if (mul) s *= mul[idx];
    outav[idx] = s;
}

// ---------------------------------------------------------------- layernorm
__global__ __launch_bounds__(256)
void ln_kernel(const u16* __restrict__ Z, const float* __restrict__ g,
               const float* __restrict__ bta, float* __restrict__ outp) {
    __shared__ float rs1[4], rs2[4];
    int row = blockIdx.x, tid = threadIdx.x;
    const u16* zr = Z + ((size_t)row << 10);
    ushort4 uv = *(const ushort4*)(zr + (tid << 2));
    float v0 = b2f(uv.x), v1 = b2f(uv.y), v2 = b2f(uv.z), v3 = b2f(uv.w);
    float s = v0 + v1 + v2 + v3;
    float s2 = v0 * v0 + v1 * v1 + v2 * v2 + v3 * v3;
    for (int o = 32; o; o >>= 1) { s += __shfl_xor(s, o); s2 += __shfl_xor(s2, o); }
    if ((tid & 63) == 0) { rs1[tid >> 6] = s; rs2[tid >> 6] = s2; }
    __syncthreads();
    float S = rs1[0] + rs1[1] + rs1[2] + rs1[3];
    float S2 = rs2[0] + rs2[1] + rs2[2] + rs2[3];
    float mean = S * (1.0f / 1024.0f);
    float var = S2 * (1.0f / 1024.0f) - mean * mean;
    float inv = rsqrtf(var + 1e-6f);
    int c = tid << 2;
    float4 o4;
    o4.x = (v0 - mean) * inv * g[c + 0] + bta[c + 0];
    o4.y = (v1 - mean) * inv * g[c + 1] + bta[c + 1];
    o4.z = (v2 - mean) * inv * g[c + 2] + bta[c + 2];
    o4.w = (v3 - mean) * inv * g[c + 3] + bta[c + 3];
    *(float4*)(outp + ((size_t)row << 10) + c) = o4;
}

// ---------------------------------------------------------------- launch

extern "C" void kernel_launch(void* const* d_in, const int* in_sizes, int n_in,
                              void* d_out, int out_size, void* d_ws, size_t ws_size,
                              hipStream_t stream) {
    (void)in_sizes; (void)n_in; (void)out_size;
    const float* x    = (const float*)d_in[0];
    const float* mask = (const float*)d_in[1];
    const float* Wq   = (const float*)d_in[2];
    const float* bq   = (const float*)d_in[3];
    const float* Wk   = (const float*)d_in[4];
    const float* bk   = (const float*)d_in[5];
    const float* Wv   = (const float*)d_in[6];
    const float* bv   = (const float*)d_in[7];
    const float* Wa   = (const float*)d_in[8];
    const float* ba   = (const float*)d_in[9];
    const float* Wb   = (const float*)d_in[10];
    const float* bb   = (const float*)d_in[11];
    const float* Wu   = (const float*)d_in[12];
    const float* bu   = (const float*)d_in[13];
    const float* Wo   = (const float*)d_in[14];
    const float* bo   = (const float*)d_in[15];
    const float* ln_g = (const float*)d_in[16];
    const float* ln_b = (const float*)d_in[17];
    float* outp = (float*)d_out;

    char* ws = (char*)d_ws;
    // layout (bytes, all 256-aligned)
    u16*   xb    = (u16*)(ws);                     //  67,108,864  x bf16; later aliased by z
    u16*   qkv   = (u16*)(ws + 67108864);          // 201,326,592  [32768][3072]; q-region aliased by t
    u16*   Wqkvt = (u16*)(ws + 268435456);         //   6,291,456
    u16*   Wot   = (u16*)(ws + 274726912);         //   2,097,152
    u16*   Wat   = (u16*)(ws + 276824064);         //      32,768
    u16*   Wbt   = (u16*)(ws + 276856832);         //     262,144
    float* score = (float*)(ws + 277118976);       //   2,097,152 (reused for a & b scores)
    float* q_av  = (float*)(ws + 279216128);       //      32,768
    float* p_av  = (float*)(ws + 279248896);       //      32,768
    float* biasq = (float*)(ws + 279281664);       //      12,288
    u16*   Wubt  = (u16*)(ws + 279293952);         //  16,777,216
    float* part  = (float*)(ws + 296071168);       //     262,144  pool partials
    float* pmax  = (float*)(ws + 296333312);       //      32,768  per-block score maxes
    float* parte = (float*)(ws + 296366080);       //       4,096  exp-sum partials -> total 296,370,176
    if (ws_size < 296370176ULL) return;

    // fused x-conversion + weight prep (one launch)
    prep_all<<<17484, 256, 0, stream>>>(x, xb, Wq, Wk, Wv, Wo, Wqkvt, Wot,
                                        Wa, Wat, bq, bk, bv, biasq);

    // qkv = x @ [Wq|Wk|Wv] + bias   (M=32768, N=3072, K=1024)
    gemm_bf16<<<6144, 256, 0, stream>>>(xb, 1024, Wqkvt, biasq,
                                        nullptr, 0, qkv, 3072, 3072, 1024, 0);
    // ascore (+ per-block maxes)
    score_gemm<<<512, 256, 0, stream>>>(qkv, 3072, Wat, ba, mask, score, pmax, 0);
    // alpha pool (softmax folded in) -> q_av
    pool_sum<<<1024, 256, 0, stream>>>(score, pmax, qkv, 3072, part, parte);
    pool_finalize<<<32, 256, 0, stream>>>(part, parte, nullptr, q_av);
    // per-batch Wb' = diag(q_av) Wb
    wbt_prep<<<512, 256, 0, stream>>>(Wb, q_av, Wbt);
    // bscore = k @ Wb'
    score_gemm<<<512, 256, 0, stream>>>(qkv + 1024, 3072, Wbt, bb, mask, score, pmax, 1);
    // beta pool, times q_av -> p_av
    pool_sum<<<1024, 256, 0, stream>>>(score, pmax, qkv + 1024, 3072, part, parte);
    pool_finalize<<<32, 256, 0, stream>>>(part, parte, q_av, p_av);
    // per-batch Wu' = diag(p_av) Wu (transposed, bf16)
    wu_prime<<<256, 256, 0, stream>>>(Wu, p_av, Wubt);
    // t = v @ Wu'_b + bu + q   (writes over q region; element read-before-write)
    gemm_bf16<<<2048, 256, 0, stream>>>(qkv + 2048, 3072, Wubt, bu,
                                        qkv, 3072, qkv, 3072, 1024, 1024, 4096);
    // z = t @ Wo^T + bo + x    (writes over xb; element read-before-write)
    gemm_bf16<<<2048, 256, 0, stream>>>(qkv, 3072, Wot, bo,
                                        xb, 1024, xb, 1024, 1024, 1024, 0);
    // layernorm -> out (f32)
    ln_kernel<<<32768, 256, 0, stream>>>(xb, ln_g, ln_b, outp);
}

// Round 7
// 743.978 us; speedup vs baseline: 1.2682x; 1.0259x over previous
//
#include <hip/hip_runtime.h>

typedef unsigned short u16;
typedef __bf16 bf16x8 __attribute__((ext_vector_type(8)));
typedef float  f32x4  __attribute__((ext_vector_type(4)));

__device__ __forceinline__ float b2f(u16 u) {
    unsigned int v = ((unsigned int)u) << 16;
    return __builtin_bit_cast(float, v);
}
__device__ __forceinline__ u16 f2b(float f) {
    unsigned int v = __builtin_bit_cast(unsigned int, f);
    v += 0x7fffu + ((v >> 16) & 1u);
    return (u16)(v >> 16);
}

// async global->LDS, 16B per lane; LDS dest = wave-uniform base + lane*16
#define GLD16(gp, lp) __builtin_amdgcn_global_load_lds( \
    (const __attribute__((address_space(1))) void*)(gp), \
    (__attribute__((address_space(3))) void*)(lp), 16, 0, 0)

// ---------------------------------------------------------------- prep kernels

// fused: blocks 0..16383 convert x f32->bf16; 16384..17407 transpose
// {Wq,Wk,Wv,Wo}; 17408..17471 wat; 17472..17483 bias concat.
__global__ __launch_bounds__(256)
void prep_all(const float* __restrict__ x, u16* __restrict__ xb,
              const float* __restrict__ Wq, const float* __restrict__ Wk,
              const float* __restrict__ Wv, const float* __restrict__ Wo,
              u16* __restrict__ Wqkvt, u16* __restrict__ Wot,
              const float* __restrict__ Wa, u16* __restrict__ Wat,
              const float* __restrict__ bq, const float* __restrict__ bk,
              const float* __restrict__ bv, float* __restrict__ biasq) {
    __shared__ float tile[64][65];
    int blk = blockIdx.x;
    int tid = threadIdx.x;
    if (blk < 16384) {
        size_t i = ((size_t)blk * 256 + tid) * 8;
        float4 v0 = *(const float4*)(x + i);
        float4 v1 = *(const float4*)(x + i + 4);
        ushort4 o0, o1;
        o0.x = f2b(v0.x); o0.y = f2b(v0.y); o0.z = f2b(v0.z); o0.w = f2b(v0.w);
        o1.x = f2b(v1.x); o1.y = f2b(v1.y); o1.z = f2b(v1.z); o1.w = f2b(v1.w);
        *(ushort4*)(xb + i)     = o0;
        *(ushort4*)(xb + i + 4) = o1;
        return;
    }
    int wblk = blk - 16384;
    if (wblk < 1024) {
        int g = wblk >> 8;
        int lb = wblk & 255;
        const float* W = (g == 0) ? Wq : (g == 1) ? Wk : (g == 2) ? Wv : Wo;
        u16* Wt = (g == 3) ? Wot : (Wqkvt + (size_t)g * 1048576);
        int kt = (lb & 15) * 64;
        int nt = (lb >> 4) * 64;
        int r = tid >> 4, c4 = (tid & 15) * 4;
        #pragma unroll
        for (int p = 0; p < 4; ++p) {
            int k = kt + p * 16 + r;
            float4 v = *(const float4*)(W + (size_t)k * 1024 + nt + c4);
            tile[c4 + 0][p * 16 + r] = v.x;
            tile[c4 + 1][p * 16 + r] = v.y;
            tile[c4 + 2][p * 16 + r] = v.z;
            tile[c4 + 3][p * 16 + r] = v.w;
        }
        __syncthreads();
        #pragma unroll
        for (int p = 0; p < 4; ++p) {
            int nl = p * 16 + r;
            ushort4 o;
            o.x = f2b(tile[nl][c4 + 0]); o.y = f2b(tile[nl][c4 + 1]);
            o.z = f2b(tile[nl][c4 + 2]); o.w = f2b(tile[nl][c4 + 3]);
            *(ushort4*)(Wt + (size_t)(nt + nl) * 1024 + kt + c4) = o;
        }
    } else if (wblk < 1088) {
        int idx = (wblk - 1024) * 256 + tid;   // 16384 = 16 h * 1024 k
        int h = idx >> 10, k = idx & 1023;
        Wat[idx] = f2b(Wa[(k << 4) + h]);
    } else {
        int i = (wblk - 1088) * 256 + tid;     // 3072
        biasq[i] = (i < 1024) ? bq[i] : (i < 2048 ? bk[i - 1024] : bv[i - 2048]);
    }
}

// Wut[b][n][k] = bf16(Wu[k][n] * p_av[b][k])  (fold p_av into per-batch B)
__global__ __launch_bounds__(256) void wu_prime(const float* __restrict__ Wu,
                                                const float* __restrict__ p_av,
                                                u16* __restrict__ Wut) {
    __shared__ float tile[64][65];
    int kt = (blockIdx.x & 15) * 64;
    int nt = (blockIdx.x >> 4) * 64;
    int tid = threadIdx.x;
    int r = tid >> 4, c4 = (tid & 15) * 4;
    #pragma unroll
    for (int p = 0; p < 4; ++p) {
        int k = kt + p * 16 + r;
        float4 v = *(const float4*)(Wu + (size_t)k * 1024 + nt + c4);
        tile[c4 + 0][p * 16 + r] = v.x;
        tile[c4 + 1][p * 16 + r] = v.y;
        tile[c4 + 2][p * 16 + r] = v.z;
        tile[c4 + 3][p * 16 + r] = v.w;
    }
    __syncthreads();
    for (int b = 0; b < 8; ++b) {
        float4 pv = *(const float4*)(p_av + (size_t)b * 1024 + kt + c4);
        #pragma unroll
        for (int p = 0; p < 4; ++p) {
            int nl = p * 16 + r;
            ushort4 o;
            o.x = f2b(tile[nl][c4 + 0] * pv.x);
            o.y = f2b(tile[nl][c4 + 1] * pv.y);
            o.z = f2b(tile[nl][c4 + 2] * pv.z);
            o.w = f2b(tile[nl][c4 + 3] * pv.w);
            *(ushort4*)(Wut + ((size_t)b * 1024 + nt + nl) * 1024 + kt + c4) = o;
        }
    }
}

// Wbt[b][h][k] = bf16(Wb[k][h] * q_av[b][k])
__global__ __launch_bounds__(256) void wbt_prep(const float* __restrict__ Wb,
                                                const float* __restrict__ q_av,
                                                u16* __restrict__ Wbt) {
    int idx = blockIdx.x * 256 + threadIdx.x;   // 131072
    int b = idx >> 14, rem = idx & 16383;
    int h = rem >> 10, k = rem & 1023;
    Wbt[idx] = f2b(Wb[(k << 4) + h] * q_av[(b << 10) + k]);
}

// ---------------------------------------------------------------- main GEMM
// 128x128 tile, BK=64, XOR-swizzled LDS (0 bank conflicts, verified),
// global_load_lds width=16, XCD-aware swizzle + 8x2 supertile ordering:
// within an XCD, 16-block squares cover 8 tm x 2 tn; consecutive squares sweep
// tn-pairs inside one tm-octet band, so the band's A (2 MB) is L2-resident and
// B is re-streamed only once per band (4 bands/XCD at mper=32).
// R6 measured: 2x2 supertile cut FETCH 470->385 MB, dur 237->216 us.
__global__ __launch_bounds__(256, 4)
void gemm_bf16(const u16* __restrict__ A, int lda,
               const u16* __restrict__ Bt,        // [N][K] bf16 (B^T)
               const float* __restrict__ bias,    // [N]
               const u16* __restrict__ addsrc, int ldadd,  // optional epilogue add
               u16* __restrict__ C, int ldc,
               int N, int K, int batch_rows) {    // batch_rows>0: Bt per-batch
    __shared__ u16 As[128 * 64];   // 16 KB, rows of 128 B, XOR-swizzled k-groups
    __shared__ u16 Bs[128 * 64];
    int ntiles = N >> 7;
    int bid = blockIdx.x;
    int mtiles = gridDim.x / ntiles;
    int tm, tn;
    if ((mtiles & 7) == 0) {
        int xcd = bid & 7, s = bid >> 3;
        int mper = mtiles >> 3;
        if (((mper & 7) | (ntiles & 1)) == 0) {
            // 8x2 supertile: square r = s&15 covers 8 tm x 2 tn; sq = s>>4
            // sweeps tn-pairs fastest within a tm-octet band.
            int half = ntiles >> 1;
            int sq = s >> 4, r = s & 15;
            int band = sq / half, tnp = sq - band * half;
            tm = xcd * mper + (band << 3) + (r >> 1);
            tn = (tnp << 1) + (r & 1);
        } else if (((mper | ntiles) & 1) == 0) {
            int half = ntiles >> 1;
            int sq = s >> 2, r = s & 3;
            tm = xcd * mper + ((sq / half) << 1) + (r >> 1);
            tn = ((sq - (sq / half) * half) << 1) + (r & 1);
        } else {
            tm = xcd * mper + s / ntiles;
            tn = s - (s / ntiles) * ntiles;
        }
    } else {
        tm = bid / ntiles; tn = bid - (bid / ntiles) * ntiles;
    }
    int m0 = tm << 7, n0 = tn << 7;
    if (batch_rows > 0) Bt += (size_t)(m0 / batch_rows) * (size_t)N * K;
    int tid = threadIdx.x, lane = tid & 63, w = tid >> 6;
    int wm = (w >> 1) << 6, wn = (w & 1) << 6;
    int quad = lane >> 4, l16 = lane & 15;
    int rph = l16 & 7;                 // row phase for XOR swizzle
    int lrow = lane >> 3;              // 0..7: row within 8-row chunk
    int lkg  = (lane & 7) ^ lrow;      // global k-group this lane fetches

    int idxA = (m0 + (w << 5) + lrow) * lda + (lkg << 3);
    int idxB = (n0 + (w << 5) + lrow) * K   + (lkg << 3);
    int stepA = lda << 3, stepB = K << 3;   // 8 rows of elements

    f32x4 zero = {0.f, 0.f, 0.f, 0.f};
    f32x4 acc[4][4];
    #pragma unroll
    for (int i = 0; i < 4; ++i)
        #pragma unroll
        for (int j = 0; j < 4; ++j) acc[i][j] = zero;

    for (int kt = 0; kt < K; kt += 64) {
        __syncthreads();
        #pragma unroll
        for (int j = 0; j < 4; ++j) {
            int c = (w << 2) + j;
            GLD16(A  + (idxA + j * stepA + kt), &As[c << 9]);
            GLD16(Bt + (idxB + j * stepB + kt), &Bs[c << 9]);
        }
        __syncthreads();
        #pragma unroll
        for (int kk = 0; kk < 2; ++kk) {
            bf16x8 a[4], b[4];
            int kg = (((kk << 2) + quad) ^ rph) << 3;  // swizzled k-offset (u16)
            #pragma unroll
            for (int i = 0; i < 4; ++i) {
                a[i] = *(const bf16x8*)&As[((wm + (i << 4) + l16) << 6) + kg];
                b[i] = *(const bf16x8*)&Bs[((wn + (i << 4) + l16) << 6) + kg];
            }
            #pragma unroll
            for (int mi = 0; mi < 4; ++mi)
                #pragma unroll
                for (int ni = 0; ni < 4; ++ni)
                    acc[mi][ni] = __builtin_amdgcn_mfma_f32_16x16x32_bf16(
                        a[mi], b[ni], acc[mi][ni], 0, 0, 0);
        }
    }
    // epilogue: C/D layout col=lane&15, row=quad*4+reg (verified m89/m91).
    // addsrc loads batched per-mi ahead of the stores so vmcnt amortizes.
    #pragma unroll
    for (int mi = 0; mi < 4; ++mi) {
        u16 av[4][4];
        if (addsrc) {
            #pragma unroll
            for (int ni = 0; ni < 4; ++ni) {
                int col = n0 + wn + (ni << 4) + l16;
                #pragma unroll
                for (int rg = 0; rg < 4; ++rg) {
                    int rowg = m0 + wm + (mi << 4) + (quad << 2) + rg;
                    av[ni][rg] = addsrc[(size_t)rowg * ldadd + col];
                }
            }
        }
        #pragma unroll
        for (int ni = 0; ni < 4; ++ni) {
            int col = n0 + wn + (ni << 4) + l16;
            float bv = bias[col];
            #pragma unroll
            for (int rg = 0; rg < 4; ++rg) {
                int rowg = m0 + wm + (mi << 4) + (quad << 2) + rg;
                float vv = acc[mi][ni][rg] + bv;
                if (addsrc) vv += b2f(av[ni][rg]);
                C[(size_t)rowg * ldc + col] = f2b(vv);
            }
        }
    }
}

// ------------------------------------------------- score GEMM ([Nrows]x[16])
// out[b][h][s] = 0.125*(dot(A_row, Bt[h]) + bias16[h]) + mask[b][s]
// Also emits pmax[bh][sblk] = max over this block's 64 s-values (per h),
// so softmax needs no separate max pass. 64 rows/block -> 512 blocks.
__global__ __launch_bounds__(256)
void score_gemm(const u16* __restrict__ A, int lda,
                const u16* __restrict__ Bt,     // [16][1024] bf16 (per batch if batched)
                const float* __restrict__ bias16,
                const float* __restrict__ mask, // [8][4096]
                float* __restrict__ outsc,      // [8][16][4096]
                float* __restrict__ pmax,       // [128][64]
                int batched) {
    __shared__ u16 As[64 * 64];    // 8 KB
    __shared__ u16 Bs[16 * 64];    // 2 KB
    __shared__ float pm[16][16];   // [w*4+quad][h]
    int m0 = blockIdx.x << 6;      // 64 rows per block (4096%64==0: no batch straddle)
    int tid = threadIdx.x, lane = tid & 63, w = tid >> 6;
    int quad = lane >> 4, l16 = lane & 15;
    int rph = l16 & 7;
    int lrow = lane >> 3;
    int lkg  = (lane & 7) ^ lrow;
    const u16* Bb = Bt + (batched ? ((size_t)(m0 >> 12) << 14) : 0);

    int idxA = (m0 + (w << 4) + lrow) * lda + (lkg << 3);  // chunk c=w*2+j, rows c*8+lrow
    int stepA = lda << 3;
    int idxB = lrow * 1024 + (lkg << 3);                    // rows h = w*8+lrow

    f32x4 acc4 = (f32x4){0.f, 0.f, 0.f, 0.f};

    for (int kt = 0; kt < 1024; kt += 64) {
        __syncthreads();
        #pragma unroll
        for (int j = 0; j < 2; ++j) {
            int c = (w << 1) + j;
            GLD16(A + (idxA + j * stepA + kt), &As[c << 9]);
        }
        if (w < 2)
            GLD16(Bb + (idxB + w * 8192 + kt), &Bs[w << 9]);
        __syncthreads();
        #pragma unroll
        for (int kk = 0; kk < 2; ++kk) {
            int kg = (((kk << 2) + quad) ^ rph) << 3;
            bf16x8 b = *(const bf16x8*)&Bs[(l16 << 6) + kg];
            bf16x8 a = *(const bf16x8*)&As[(((w << 4) + l16) << 6) + kg];
            acc4 = __builtin_amdgcn_mfma_f32_16x16x32_bf16(a, b, acc4, 0, 0, 0);
        }
    }
    int bidx = m0 >> 12;
    float bv = bias16[l16];
    float* orow = outsc + (((size_t)bidx << 4) + l16) * 4096;
    const float* mrow = mask + ((size_t)bidx << 12);
    int sbase = (m0 & 4095) + (w << 4) + (quad << 2);
    float lm = -1e30f;
    #pragma unroll
    for (int rg = 0; rg < 4; ++rg) {
        float sv = 0.125f * (acc4[rg] + bv) + mrow[sbase + rg];
        orow[sbase + rg] = sv;
        lm = fmaxf(lm, sv);
    }
    pm[(w << 2) | quad][l16] = lm;
    __syncthreads();
    if (tid < 16) {
        float m = pm[0][tid];
        #pragma unroll
        for (int j = 1; j < 16; ++j) m = fmaxf(m, pm[j][tid]);
        pmax[(((bidx << 4) + tid) << 6) + (blockIdx.x & 63)] = m;
    }
}

// --------------------------- weighted pool partials: 1024 blocks = (b,h,chunk)
// Reads raw scores + pmax; applies exp(s - rowmax) on the fly; accumulates
// weighted sums AND exp-sum. Softmax normalization happens in pool_finalize.
__global__ __launch_bounds__(256)
void pool_sum(const float* __restrict__ score,  // [8][16][4096] raw scores
              const float* __restrict__ pmax,   // [128][64]
              const u16* __restrict__ X, int ldx, // q or k rows, bf16
              float* __restrict__ part,          // [128][8][64] weighted partials
              float* __restrict__ parte) {       // [128][8] exp-sum partials
    __shared__ float psum[16][64];
    __shared__ float pes[16];
    __shared__ float smx;
    int blk = blockIdx.x, tid = threadIdx.x;
    int cc = blk & 7, bh = blk >> 3;            // chunk of 512 rows; (b,h)
    int b = bh >> 4, h = bh & 15;
    if (tid < 64) {
        float m = pmax[(bh << 6) + tid];
        for (int o = 32; o; o >>= 1) m = fmaxf(m, __shfl_xor(m, o));
        if (tid == 0) smx = m;
    }
    __syncthreads();
    float mx = smx;
    const float* wrow = score + ((size_t)bh << 12) + (cc << 9);
    int dg = (tid & 15) << 2;                   // 4 of 64 dims in head
    int sc = tid >> 4;                          // 16 sub-chunks of 32 rows
    const u16* base = X + (size_t)((b << 12) + (cc << 9) + (sc << 5)) * ldx + (h << 6) + dg;
    float a0 = 0, a1 = 0, a2 = 0, a3 = 0, es = 0;
    for (int s = 0; s < 32; ++s) {
        float e = __expf(wrow[(sc << 5) + s] - mx);
        es += e;
        ushort4 uv = *(const ushort4*)(base + (size_t)s * ldx);
        a0 += e * b2f(uv.x); a1 += e * b2f(uv.y);
        a2 += e * b2f(uv.z); a3 += e * b2f(uv.w);
    }
    psum[sc][dg + 0] = a0; psum[sc][dg + 1] = a1;
    psum[sc][dg + 2] = a2; psum[sc][dg + 3] = a3;
    if ((tid & 15) == 0) pes[sc] = es;
    __syncthreads();
    if (tid < 64) {
        float t = 0.f;
        #pragma unroll
        for (int j = 0; j < 16; ++j) t += psum[j][tid];
        part[(((size_t)bh << 3) + cc) * 64 + tid] = t;
    }
    if (tid == 64) {
        float e = 0.f;
        #pragma unroll
        for (int j = 0; j < 16; ++j) e += pes[j];
        parte[(bh << 3) + cc] = e;
    }
}

// sum the 8 chunk-partials, divide by total exp-sum; optional multiply
__global__ __launch_bounds__(256)
void pool_finalize(const float* __restrict__ part,   // [128][8][64]
                   const float* __restrict__ parte,  // [128][8]
                   const float* __restrict__ mul,    // null or [8][1024]
                   float* __restrict__ outav) {      // [8][1024]
    int idx = blockIdx.x * 256 + threadIdx.x;        // 8192
    int bh = idx >> 6;
    const float* p = part + ((size_t)bh << 9) + (idx & 63);
    const float* pe = parte + (bh << 3);
    float s = 0.f, e = 0.f;
    #pragma unroll
    for (int c = 0; c < 8; ++c) { s += p[c << 6]; e += pe[c]; }
    s /= e;
    if (mul) s *= mul[idx];
    outav[idx] = s;
}

// ---------------------------------------------------------------- layernorm
__global__ __launch_bounds__(256)
void ln_kernel(const u16* __restrict__ Z, const float* __restrict__ g,
               const float* __restrict__ bta, float* __restrict__ outp) {
    __shared__ float rs1[4], rs2[4];
    int row = blockIdx.x, tid = threadIdx.x;
    const u16* zr = Z + ((size_t)row << 10);
    ushort4 uv = *(const ushort4*)(zr + (tid << 2));
    float v0 = b2f(uv.x), v1 = b2f(uv.y), v2 = b2f(uv.z), v3 = b2f(uv.w);
    float s = v0 + v1 + v2 + v3;
    float s2 = v0 * v0 + v1 * v1 + v2 * v2 + v3 * v3;
    for (int o = 32; o; o >>= 1) { s += __shfl_xor(s, o); s2 += __shfl_xor(s2, o); }
    if ((tid & 63) == 0) { rs1[tid >> 6] = s; rs2[tid >> 6] = s2; }
    __syncthreads();
    float S = rs1[0] + rs1[1] + rs1[2] + rs1[3];
    float S2 = rs2[0] + rs2[1] + rs2[2] + rs2[3];
    float mean = S * (1.0f / 1024.0f);
    float var = S2 * (1.0f / 1024.0f) - mean * mean;
    float inv = rsqrtf(var + 1e-6f);
    int c = tid << 2;
    float4 o4;
    o4.x = (v0 - mean) * inv * g[c + 0] + bta[c + 0];
    o4.y = (v1 - mean) * inv * g[c + 1] + bta[c + 1];
    o4.z = (v2 - mean) * inv * g[c + 2] + bta[c + 2];
    o4.w = (v3 - mean) * inv * g[c + 3] + bta[c + 3];
    *(float4*)(outp + ((size_t)row << 10) + c) = o4;
}

// ---------------------------------------------------------------- launch

extern "C" void kernel_launch(void* const* d_in, const int* in_sizes, int n_in,
                              void* d_out, int out_size, void* d_ws, size_t ws_size,
                              hipStream_t stream) {
    (void)in_sizes; (void)n_in; (void)out_size;
    const float* x    = (const float*)d_in[0];
    const float* mask = (const float*)d_in[1];
    const float* Wq   = (const float*)d_in[2];
    const float* bq   = (const float*)d_in[3];
    const float* Wk   = (const float*)d_in[4];
    const float* bk   = (const float*)d_in[5];
    const float* Wv   = (const float*)d_in[6];
    const float* bv   = (const float*)d_in[7];
    const float* Wa   = (const float*)d_in[8];
    const float* ba   = (const float*)d_in[9];
    const float* Wb   = (const float*)d_in[10];
    const float* bb   = (const float*)d_in[11];
    const float* Wu   = (const float*)d_in[12];
    const float* bu   = (const float*)d_in[13];
    const float* Wo   = (const float*)d_in[14];
    const float* bo   = (const float*)d_in[15];
    const float* ln_g = (const float*)d_in[16];
    const float* ln_b = (const float*)d_in[17];
    float* outp = (float*)d_out;

    char* ws = (char*)d_ws;
    // layout (bytes, all 256-aligned)
    u16*   xb    = (u16*)(ws);                     //  67,108,864  x bf16; later aliased by z
    u16*   qkv   = (u16*)(ws + 67108864);          // 201,326,592  [32768][3072]; q-region aliased by t
    u16*   Wqkvt = (u16*)(ws + 268435456);         //   6,291,456
    u16*   Wot   = (u16*)(ws + 274726912);         //   2,097,152
    u16*   Wat   = (u16*)(ws + 276824064);         //      32,768
    u16*   Wbt   = (u16*)(ws + 276856832);         //     262,144
    float* score = (float*)(ws + 277118976);       //   2,097,152 (reused for a & b scores)
    float* q_av  = (float*)(ws + 279216128);       //      32,768
    float* p_av  = (float*)(ws + 279248896);       //      32,768
    float* biasq = (float*)(ws + 279281664);       //      12,288
    u16*   Wubt  = (u16*)(ws + 279293952);         //  16,777,216
    float* part  = (float*)(ws + 296071168);       //     262,144  pool partials
    float* pmax  = (float*)(ws + 296333312);       //      32,768  per-block score maxes
    float* parte = (float*)(ws + 296366080);       //       4,096  exp-sum partials -> total 296,370,176
    if (ws_size < 296370176ULL) return;

    // fused x-conversion + weight prep (one launch)
    prep_all<<<17484, 256, 0, stream>>>(x, xb, Wq, Wk, Wv, Wo, Wqkvt, Wot,
                                        Wa, Wat, bq, bk, bv, biasq);

    // qkv = x @ [Wq|Wk|Wv] + bias   (M=32768, N=3072, K=1024)
    gemm_bf16<<<6144, 256, 0, stream>>>(xb, 1024, Wqkvt, biasq,
                                        nullptr, 0, qkv, 3072, 3072, 1024, 0);
    // ascore (+ per-block maxes)
    score_gemm<<<512, 256, 0, stream>>>(qkv, 3072, Wat, ba, mask, score, pmax, 0);
    // alpha pool (softmax folded in) -> q_av
    pool_sum<<<1024, 256, 0, stream>>>(score, pmax, qkv, 3072, part, parte);
    pool_finalize<<<32, 256, 0, stream>>>(part, parte, nullptr, q_av);
    // per-batch Wb' = diag(q_av) Wb
    wbt_prep<<<512, 256, 0, stream>>>(Wb, q_av, Wbt);
    // bscore = k @ Wb'
    score_gemm<<<512, 256, 0, stream>>>(qkv + 1024, 3072, Wbt, bb, mask, score, pmax, 1);
    // beta pool, times q_av -> p_av
    pool_sum<<<1024, 256, 0, stream>>>(score, pmax, qkv + 1024, 3072, part, parte);
    pool_finalize<<<32, 256, 0, stream>>>(part, parte, q_av, p_av);
    // per-batch Wu' = diag(p_av) Wu (transposed, bf16)
    wu_prime<<<256, 256, 0, stream>>>(Wu, p_av, Wubt);
    // t = v @ Wu'_b + bu + q   (writes over q region; element read-before-write)
    gemm_bf16<<<2048, 256, 0, stream>>>(qkv + 2048, 3072, Wubt, bu,
                                        qkv, 3072, qkv, 3072, 1024, 1024, 4096);
    // z = t @ Wo^T + bo + x    (writes over xb; element read-before-write)
    gemm_bf16<<<2048, 256, 0, stream>>>(qkv, 3072, Wot, bo,
                                        xb, 1024, xb, 1024, 1024, 1024, 0);
    // layernorm -> out (f32)
    ln_kernel<<<32768, 256, 0, stream>>>(xb, ln_g, ln_b, outp);
}